// Round 14
// baseline (144.306 us; speedup 1.0000x reference)
//
#include <hip/hip_runtime.h>
#include <math.h>

// KSpaceResampling: type-2 NUDFT -> ramp weights -> type-1 adjoint -> abs
// R14: kill the 39MB Aadj round-trip — tmat folded INTO adj_gemm (A-fragments
// computed in-register from combos/CxT/SxT with identical f2b arithmetic ->
// bit-identical output). Fixes R8's failure: same-kc blocks are kc-per-XCD
// grouped so table reads are L2-shared (R8 scattered them -> 77MB HBM).
// combine2 reinstated (packed p/q rows + pad zeroing + K2edge, R11-validated).

#define HH 192
#define WW 192
#define NVIEWS 128
#define NSAMP 384
#define NPIX (HH*WW)      // 36864
#define HALFT 193         // stored t = 0..192
#define M2 12545          // 65 * 193  (v2 in [0,64])
#define M2P 12672         // padded
#define KTOT 25344        // 2 * M2P   (adjoint GEMM K: Cy-part ; Sy-part)
#define NSPLITK 33        // adjoint GEMM K-split (25344/33 = 768)

typedef __attribute__((ext_vector_type(8))) short bf16x8;
typedef __attribute__((ext_vector_type(4))) float f32x4;
typedef __attribute__((ext_vector_type(8))) unsigned short u16x8;

__device__ __forceinline__ void rot(float& cr, float& ci, float dr, float di) {
  float nr = cr*dr - ci*di;
  float ni = cr*di + ci*dr;
  cr = nr; ci = ni;
}
__device__ __forceinline__ unsigned short f2b(float f) {
  unsigned int u = __float_as_uint(f);
  u += 0x7fffu + ((u >> 16) & 1u);
  return (unsigned short)(u >> 16);
}
__device__ __forceinline__ float b2f(unsigned short h) {
  return __uint_as_float(((unsigned int)h) << 16);
}

// ---------------- phase tables + xprep + kyv (merged, 16-iter rotors) -------
// role = blockIdx.y: [0,12) x-tables (16 h each); [12,24) y-tables (16 w each);
// 24 = xprep + kyv (grid-stride).
__global__ __launch_bounds__(256) void phase_kernel(
    const float* __restrict__ points, const float* __restrict__ x,
    unsigned short* __restrict__ BT, unsigned short* __restrict__ CxT,
    unsigned short* __restrict__ SxT, unsigned short* __restrict__ Am,
    unsigned short* __restrict__ XT, float* __restrict__ kyv) {
  const int v2 = blockIdx.x;
  const int role = blockIdx.y;
  const int t = threadIdx.x;
  if (role == 24) {
    for (int idx = v2*256 + t; idx < 768*192; idx += 65*256) {
      const int n = idx / 192, h = idx - n*192;
      const int cb = n / 192, w = n - cb*192;
      const int b = cb >> 1, c = cb & 1;
      XT[idx] = f2b(x[(((size_t)b*HH + h)*WW + w)*2 + c]);
    }
    for (int idx = v2*256 + t; idx < M2P; idx += 65*256) {
      if (idx < M2) {
        const int v2b = idx / HALFT, tb = idx - v2b*HALFT;
        kyv[idx] = points[(v2b*NSAMP + tb)*2 + 1];
      } else {
        kyv[idx] = 0.f;
      }
    }
    return;
  }
  if (t >= HALFT) return;
  if (role < 12) {
    const int hsplit = role;
    const float kx = points[(v2*NSAMP + t)*2 + 0];
    const int m2 = v2*HALFT + t;
    const int h0 = hsplit*16;
    float cr, ci; __sincosf(kx*(float)(h0-96), &ci, &cr);
    float dr, di; __sincosf(kx, &di, &dr);
    u16x8 pc, ps;
    #pragma unroll
    for (int j = 0; j < 16; ++j) {
      const int h = h0 + j;
      CxT[(size_t)h*M2P + m2] = f2b(cr);
      SxT[(size_t)h*M2P + m2] = f2b(ci);
      pc[j&7] = f2b(cr); ps[j&7] = f2b(ci);
      if ((j&7) == 7) {
        *(u16x8*)(Am + (size_t)m2*192 + (h-7))         = pc;
        *(u16x8*)(Am + (size_t)(12672+m2)*192 + (h-7)) = ps;
      }
      rot(cr, ci, dr, di);
    }
  } else {
    const int wsplit = role - 12;
    const float ky = points[(v2*NSAMP + t)*2 + 1];
    const int kap = v2*HALFT + t;
    const int w0 = wsplit*16;
    float cr, ci; __sincosf(ky*(float)(w0-96), &ci, &cr);
    float dr, di; __sincosf(ky, &di, &dr);
    #pragma unroll
    for (int j = 0; j < 16; ++j) {
      BT[(size_t)(w0+j)*KTOT + kap]       = f2b(cr);
      BT[(size_t)(w0+j)*KTOT + M2P + kap] = f2b(ci);
      rot(cr, ci, dr, di);
    }
  }
}

// ---------------- forward: fused gemm1 (+ w-phase contraction) ----------------

// XCD-swizzled 1D grid (792): idx = (L&7)*99 + (L>>3); mt = idx>>2; cb = idx&3.
__global__ __launch_bounds__(256) void gemm1_kernel(
    const unsigned short* __restrict__ Am, const unsigned short* __restrict__ XT,
    const float* __restrict__ kyv, float* __restrict__ Abuf) {
  __shared__ float lds[2][128][2];
  const int L = blockIdx.x;
  const int idx0 = (L & 7)*99 + (L >> 3);
  const int mt = idx0 >> 2;           // 0..197
  const int cb = idx0 & 3;            // 0..3
  const int wv = threadIdx.x >> 6;
  const int lane = threadIdx.x & 63;
  const int r = lane & 15, kg = lane >> 4;
  const int mhalf = wv >> 1;          // 0/1: m 64-half
  const int whalf = wv & 1;           // 0/1: w 96-half
  const int mbase = mt*128 + mhalf*64;
  const int wbase = whalf*96;
  const int nbase = cb*192 + wbase;

  f32x4 acc[4][6];
  #pragma unroll
  for (int a = 0; a < 4; ++a)
    #pragma unroll
    for (int b = 0; b < 6; ++b) acc[a][b] = (f32x4){0.f,0.f,0.f,0.f};

  const unsigned short* Ap = Am + (size_t)(mbase + r)*192 + kg*8;
  const unsigned short* Bp = XT + (size_t)(nbase + r)*192 + kg*8;
  #pragma unroll
  for (int ks = 0; ks < 6; ++ks) {
    bf16x8 af[4], bfr[6];
    #pragma unroll
    for (int mf = 0; mf < 4; ++mf)
      af[mf] = *(const bf16x8*)(Ap + (size_t)mf*16*192 + ks*32);
    #pragma unroll
    for (int nf = 0; nf < 6; ++nf)
      bfr[nf] = *(const bf16x8*)(Bp + (size_t)nf*16*192 + ks*32);
    #pragma unroll
    for (int mf = 0; mf < 4; ++mf)
      #pragma unroll
      for (int nf = 0; nf < 6; ++nf)
        acc[mf][nf] = __builtin_amdgcn_mfma_f32_16x16x32_bf16(
            af[mf], bfr[nf], acc[mf][nf], 0, 0, 0);
  }

  // in-register phase contraction over w: rotor along nf (step 16*ky)
  const bool isCx = (mt < 99);
  const int m2w = mbase - (isCx ? 0 : 12672);
  float accA[16], accB[16];
  #pragma unroll
  for (int mf = 0; mf < 4; ++mf)
    #pragma unroll
    for (int reg = 0; reg < 4; ++reg) {
      const int m2 = m2w + mf*16 + kg*4 + reg;
      const float ky = kyv[m2];        // pad entries are 0 -> harmless
      float sy, cy; __sincosf(ky*(float)(wbase + r - 96), &sy, &cy);
      float ds, dc; __sincosf(ky*16.0f, &ds, &dc);
      float a0 = 0.f, b0 = 0.f;
      #pragma unroll
      for (int nf = 0; nf < 6; ++nf) {
        const float g = acc[mf][nf][reg];
        a0 = fmaf(g, cy, a0);
        b0 = fmaf(g, sy, b0);
        rot(cy, sy, dc, ds);
      }
      accA[mf*4+reg] = a0; accB[mf*4+reg] = b0;
    }
  #pragma unroll
  for (int msk = 1; msk <= 8; msk <<= 1) {
    #pragma unroll
    for (int i = 0; i < 16; ++i) {
      accA[i] += __shfl_xor(accA[i], msk);
      accB[i] += __shfl_xor(accB[i], msk);
    }
  }
  if (r == 0) {
    #pragma unroll
    for (int mf = 0; mf < 4; ++mf)
      #pragma unroll
      for (int reg = 0; reg < 4; ++reg) {
        const int mloc = mhalf*64 + mf*16 + kg*4 + reg;
        lds[whalf][mloc][0] = accA[mf*4+reg];
        lds[whalf][mloc][1] = accB[mf*4+reg];
      }
  }
  __syncthreads();
  {
    const int tid = threadIdx.x;
    const int mloc = tid >> 1, slot = tid & 1;
    const float val = lds[0][mloc][slot] + lds[1][mloc][slot];
    const int m2 = mt*128 + mloc - (isCx ? 0 : 12672);
    const int oidx = isCx ? (slot ? 3 : 0) : (slot ? 1 : 2);
    Abuf[((size_t)cb*M2P + m2)*4 + oidx] = val;
  }
}

// Abuf -> packed combos (P/Q fragment coefficients) + K2edge.
// combos rows per cb: +0=p0 (P cos), +1=p1 (P sin), +2=q0 (Q cos), +3=q1 (Q sin)
//   A_P = p0*cx + p1*sx ; A_Q = q0*cx + q1*sx   (validated R8/R11)
// Pad columns m2 in [M2,M2P) zeroed -> fused GEMM fragments become f2b(0)=0.
__global__ __launch_bounds__(256) void combine2_kernel(
    const float* __restrict__ Abuf, const float* __restrict__ weights,
    float* __restrict__ combos, float* __restrict__ K2edge) {
  const int m2 = blockIdx.x*256 + threadIdx.x;
  if (m2 >= M2P) return;
  if (m2 >= M2) {
    #pragma unroll
    for (int q = 0; q < 16; ++q) combos[(size_t)q*M2P + m2] = 0.f;
    return;
  }
  const int v2 = m2 / HALFT, t = m2 - v2*HALFT;
  float f = weights[t] * (1.0f/36864.0f);
  if (t != 0 && t != 192) f *= 2.0f;
  const bool hp = (v2 >= 1 && v2 <= 63);
  #pragma unroll
  for (int cb = 0; cb < 4; ++cb) {
    const float4 A = *(const float4*)(Abuf + ((size_t)cb*M2P + m2)*4);
    const float A1 = A.x, A2 = A.y, A3 = A.z, A4 = A.w;
    float p0, p1, q0, q1;
    if (hp) {
      p0 = 2.f*f*A1; p1 = 2.f*f*A3; q0 = 2.f*f*A4; q1 = 2.f*f*A2;
    } else {
      const float kr = f*(A1 - A2), ki = -f*(A3 + A4);
      p0 = kr; p1 = -ki; q0 = -ki; q1 = -kr;
    }
    combos[(size_t)(cb*4+0)*M2P + m2] = p0;
    combos[(size_t)(cb*4+1)*M2P + m2] = p1;
    combos[(size_t)(cb*4+2)*M2P + m2] = q0;
    combos[(size_t)(cb*4+3)*M2P + m2] = q1;
    if (t == 0 || t == 192) {
      const int d = (t == 0) ? 0 : 1;
      const float fe = weights[t] * (1.0f/36864.0f);
      float* e = K2edge + ((v2*2 + d)*4 + cb)*2;
      e[0] = fe*(A1 - A2); e[1] = -fe*(A3 + A4);
      if (hp) {
        float* e2 = K2edge + (((128 - v2)*2 + d)*4 + cb)*2;
        e2[0] = fe*(A1 + A2); e2[1] = fe*(A3 - A4);
      }
    }
  }
}

// ---------------- adjoint: fused tmat + GEMM (A never materialized) ---------
// Grid 240, kc-per-XCD (xcd = L&7 -> kc = g*8+xcd): the 6 same-kc blocks share
// their CxT/SxT/combos k-columns in one XCD's L2. A-fragment per (ks,mf):
//   af[e] = f2b(pcos[m2c+e]*cx[h][m2c+e] + psin[m2c+e]*sx[h][m2c+e])
// Same arithmetic as R12's tmat -> bit-identical A -> bit-identical output.
// P/Q selection uniform per (kc,ks) (boundary M2P is 32-aligned; kg*8 < 32).
__global__ __launch_bounds__(256) void adj_gemm(
    const float* __restrict__ combos, const unsigned short* __restrict__ CxT,
    const unsigned short* __restrict__ SxT, const unsigned short* __restrict__ BT,
    float* __restrict__ partials) {
  const int L = blockIdx.x;
  const int xcd = L & 7, slot = L >> 3;
  const int g = slot / 6;
  const int kc = g*8 + xcd;
  if (kc >= NSPLITK) return;
  const int mt = slot - g*6;
  const int wv = threadIdx.x >> 6;
  const int lane = threadIdx.x & 63;
  const int r = lane & 15, kg = lane >> 4;
  const int jbase = mt*128 + (wv>>1)*64;
  const int wbase = (wv&1)*96;
  const int kb = kc*768 + kg*8;

  f32x4 acc[4][6];
  #pragma unroll
  for (int a = 0; a < 4; ++a)
    #pragma unroll
    for (int b = 0; b < 6; ++b) acc[a][b] = (f32x4){0.f,0.f,0.f,0.f};

  const unsigned short* Bp = BT + (size_t)(wbase + r)*KTOT + kb;
  for (int ks = 0; ks < 24; ++ks) {
    bf16x8 bfr[6];
    #pragma unroll
    for (int nf = 0; nf < 6; ++nf)
      bfr[nf] = *(const bf16x8*)(Bp + (size_t)nf*16*KTOT + ks*32);

    const int kap = kb + ks*32;
    const bool isQ = (kap >= M2P);       // uniform across lanes per (kc,ks)
    const int m2c = kap - (isQ ? M2P : 0);
    const int off = isQ ? 2 : 0;

    #pragma unroll
    for (int mf = 0; mf < 4; ++mf) {
      const int j = jbase + mf*16 + r;   // 16-row span never crosses cb edge
      const int cb = j / 192;
      const int h  = j - cb*192;
      const u16x8 cxv = *(const u16x8*)(CxT + (size_t)h*M2P + m2c);
      const u16x8 sxv = *(const u16x8*)(SxT + (size_t)h*M2P + m2c);
      const float* crow = combos + (size_t)(cb*4 + off)*M2P + m2c;
      float pc[8], ps[8];
      *(float4*)&pc[0] = *(const float4*)(crow);
      *(float4*)&pc[4] = *(const float4*)(crow + 4);
      *(float4*)&ps[0] = *(const float4*)(crow + M2P);
      *(float4*)&ps[4] = *(const float4*)(crow + M2P + 4);
      u16x8 av;
      #pragma unroll
      for (int e = 0; e < 8; ++e)
        av[e] = f2b(pc[e]*b2f(cxv[e]) + ps[e]*b2f(sxv[e]));
      const bf16x8 af = *(const bf16x8*)&av;
      #pragma unroll
      for (int nf = 0; nf < 6; ++nf)
        acc[mf][nf] = __builtin_amdgcn_mfma_f32_16x16x32_bf16(
            af, bfr[nf], acc[mf][nf], 0, 0, 0);
    }
  }
  float* base = partials + (size_t)kc*192*768;
  #pragma unroll
  for (int mf = 0; mf < 4; ++mf)
    #pragma unroll
    for (int nf = 0; nf < 6; ++nf) {
      const int w = wbase + nf*16 + r;
      const int j = jbase + mf*16 + kg*4;
      *(f32x4*)(base + (size_t)w*768 + j) = acc[mf][nf];
    }
}

// finish: im (t=0 unpaired samples only) + partials K-reduction + magnitude.
__global__ __launch_bounds__(256) void finish_kernel(
    const unsigned short* __restrict__ BT, const unsigned short* __restrict__ CxT,
    const unsigned short* __restrict__ SxT, const float* __restrict__ K2edge,
    const float* __restrict__ partials, float* __restrict__ out) {
  __shared__ float cxs[65][8], sxs[65][8], cys[65][8], sys[65][8];
  __shared__ float redI[4][64][4], redR[4][64][4];
  const int bx = blockIdx.x;
  const int h0 = (bx/24)*8, w0 = (bx%24)*8;
  const int tid = threadIdx.x;
  for (int i = tid; i < 65*8; i += 256) {
    const int v2 = i >> 3, e = i & 7;
    const int kap = v2*HALFT;           // t = 0
    cxs[v2][e] = b2f(CxT[(size_t)(h0+e)*M2P + kap]);
    sxs[v2][e] = b2f(SxT[(size_t)(h0+e)*M2P + kap]);
    cys[v2][e] = b2f(BT[(size_t)(w0+e)*KTOT + kap]);
    sys[v2][e] = b2f(BT[(size_t)(w0+e)*KTOT + M2P + kap]);
  }
  __syncthreads();
  const int g = tid >> 6, hi = (tid >> 3) & 7, wi = tid & 7;
  const int h = h0 + hi, w = w0 + wi;
  float im[4] = {0,0,0,0};
  for (int v = g*32; v < g*32 + 32; ++v) {
    const int v2 = (v <= 64) ? v : 128 - v;
    const float sg = (v <= 64) ? 1.f : -1.f;
    const float cx = cxs[v2][hi], sx = sg*sxs[v2][hi];
    const float cy = cys[v2][wi], sy = sys[v2][wi];
    const float t1 = cx*sy + sx*cy;
    const float t2 = cx*cy - sx*sy;
    const int idx = v*16;
    #pragma unroll
    for (int cb = 0; cb < 4; ++cb)
      im[cb] += K2edge[idx + cb*2]*t1 + K2edge[idx + cb*2 + 1]*t2;
  }
  float re[4] = {0,0,0,0};
  for (int kc = g; kc < NSPLITK; kc += 4) {
    const float* p = partials + (size_t)kc*147456 + (size_t)w*768;
    #pragma unroll
    for (int cb = 0; cb < 4; ++cb)
      re[cb] += p[cb*192 + h];
  }
  const int p = tid & 63;
  #pragma unroll
  for (int cb = 0; cb < 4; ++cb) { redI[g][p][cb] = im[cb]; redR[g][p][cb] = re[cb]; }
  __syncthreads();
  if (g == 0) {
    #pragma unroll
    for (int cb = 0; cb < 4; ++cb) {
      im[cb] += redI[1][p][cb] + redI[2][p][cb] + redI[3][p][cb];
      re[cb] += redR[1][p][cb] + redR[2][p][cb] + redR[3][p][cb];
    }
    const int pix = h*192 + w;
    #pragma unroll
    for (int b = 0; b < 2; ++b)
      #pragma unroll
      for (int c = 0; c < 2; ++c) {
        const int cb = b*2 + c;
        out[((size_t)b*NPIX + pix)*2 + c] = sqrtf(re[cb]*re[cb] + im[cb]*im[cb]);
      }
  }
}

// ---------------- fallback (r2, validated) ----------------

template <int HPER>
__global__ __launch_bounds__(192) void fwd_kernel(
    const float* __restrict__ x, const float* __restrict__ points,
    float* __restrict__ kpart) {
  const int v = blockIdx.x;
  const int split = blockIdx.y;
  const int t = threadIdx.x;
  const int m = v*NSAMP + t;
  const float kx = points[2*m+0];
  const float ky = points[2*m+1];
  const int h0 = split*HPER;

  float kr[4] = {0,0,0,0}, ki[4] = {0,0,0,0};
  float cyr, cyi; __sincosf(96.0f*ky, &cyi, &cyr);
  float dyr, dyi; __sincosf(-ky, &dyi, &dyr);
  float cx0r, cx0i; __sincosf(kx*(float)(96-h0), &cx0i, &cx0r);
  float dxr, dxi; __sincosf(-kx, &dxi, &dxr);

  for (int wp = 0; wp < 96; ++wp) {
    const int w0 = wp*2;
    float g0r[4]={0,0,0,0}, g0i[4]={0,0,0,0};
    float g1r[4]={0,0,0,0}, g1i[4]={0,0,0,0};
    float cxr = cx0r, cxi = cx0i;
    const float* p0 = x + (h0*WW + w0)*2;
    const float* p1 = p0 + HH*WW*2;
    #pragma unroll 4
    for (int h = 0; h < HPER; ++h) {
      float4 a = *(const float4*)(p0 + h*(WW*2));
      float4 b = *(const float4*)(p1 + h*(WW*2));
      g0r[0] += a.x*cxr; g0i[0] += a.x*cxi;
      g0r[1] += a.y*cxr; g0i[1] += a.y*cxi;
      g1r[0] += a.z*cxr; g1i[0] += a.z*cxi;
      g1r[1] += a.w*cxr; g1i[1] += a.w*cxi;
      g0r[2] += b.x*cxr; g0i[2] += b.x*cxi;
      g0r[3] += b.y*cxr; g0i[3] += b.y*cxi;
      g1r[2] += b.z*cxr; g1i[2] += b.z*cxi;
      g1r[3] += b.w*cxr; g1i[3] += b.w*cxi;
      rot(cxr, cxi, dxr, dxi);
    }
    #pragma unroll
    for (int cb = 0; cb < 4; ++cb) {
      kr[cb] += g0r[cb]*cyr - g0i[cb]*cyi;
      ki[cb] += g0r[cb]*cyi + g0i[cb]*cyr;
    }
    rot(cyr, cyi, dyr, dyi);
    #pragma unroll
    for (int cb = 0; cb < 4; ++cb) {
      kr[cb] += g1r[cb]*cyr - g1i[cb]*cyi;
      ki[cb] += g1r[cb]*cyi + g1i[cb]*cyr;
    }
    rot(cyr, cyi, dyr, dyi);
  }
  float* o = kpart + (((split*NVIEWS + v)*192 + t)*4)*2;
  #pragma unroll
  for (int cb = 0; cb < 4; ++cb) { o[2*cb] = kr[cb]; o[2*cb+1] = ki[cb]; }
}

__global__ __launch_bounds__(256) void dc_kernel(
    const float* __restrict__ x, float* __restrict__ dcsum) {
  const int tid = threadIdx.x;
  float s0=0.f, s1=0.f, s2=0.f, s3=0.f;
  for (int i = tid; i < NPIX; i += 256) {
    float2 a = *(const float2*)(x + i*2);
    float2 b = *(const float2*)(x + HH*WW*2 + i*2);
    s0 += a.x; s1 += a.y; s2 += b.x; s3 += b.y;
  }
  #pragma unroll
  for (int off = 32; off > 0; off >>= 1) {
    s0 += __shfl_down(s0, off);
    s1 += __shfl_down(s1, off);
    s2 += __shfl_down(s2, off);
    s3 += __shfl_down(s3, off);
  }
  __shared__ float red[4][4];
  const int wv = tid >> 6, ln = tid & 63;
  if (ln == 0) { red[0][wv]=s0; red[1][wv]=s1; red[2][wv]=s2; red[3][wv]=s3; }
  __syncthreads();
  if (tid < 4) {
    float tot = red[tid][0]+red[tid][1]+red[tid][2]+red[tid][3];
    dcsum[2*tid] = tot; dcsum[2*tid+1] = 0.0f;
  }
}

__global__ __launch_bounds__(256) void combine_kernel(
    const float* __restrict__ kpart, const float* __restrict__ dcsum,
    const float* __restrict__ weights, float* __restrict__ K2, int nsplit) {
  const int idx = blockIdx.x*256 + threadIdx.x;
  if (idx >= NVIEWS*HALFT) return;
  const int v = idx / HALFT, t = idx % HALFT;
  float f = weights[t] * (1.0f/36864.0f);
  if (t != 0 && t != 192) f *= 2.0f;
  float o[8];
  if (t == 192) {
    #pragma unroll
    for (int cb = 0; cb < 4; ++cb) { o[2*cb] = f*dcsum[2*cb]; o[2*cb+1] = f*dcsum[2*cb+1]; }
  } else {
    #pragma unroll
    for (int cb = 0; cb < 4; ++cb) {
      float ar = 0.f, ai = 0.f;
      for (int s = 0; s < nsplit; ++s) {
        const float* p = kpart + (((s*NVIEWS + v)*192 + t)*4 + cb)*2;
        ar += p[0]; ai += p[1];
      }
      o[2*cb] = f*ar; o[2*cb+1] = f*ai;
    }
  }
  float* q = K2 + idx*8;
  #pragma unroll
  for (int j = 0; j < 8; ++j) q[j] = o[j];
}

template <int VPC>
__global__ __launch_bounds__(256) void adj_kernel(
    const float* __restrict__ K2, const float* __restrict__ points,
    float* __restrict__ imgpart) {
  const int pix = blockIdx.x*256 + threadIdx.x;
  const int chunk = blockIdx.y;
  const float nh = (float)(pix / WW - 96);
  const float nw = (float)(pix % WW - 96);
  float re[4] = {0,0,0,0}, im[4] = {0,0,0,0};
  const float INVPI = 0.3183098861837907f;
  const float PI192 = 3.14159265358979f / 192.0f;
  for (int v = chunk*VPC; v < chunk*VPC + VPC; ++v) {
    const float ct = -points[2*(v*NSAMP)+0] * INVPI;
    const float st = -points[2*(v*NSAMP)+1] * INVPI;
    const float alpha = ct*nh + st*nw;
    const float delta = alpha * PI192;
    float dr, di; __sincosf(delta, &di, &dr);
    float c0r, c0i; __sincosf(-192.0f*delta, &c0i, &c0r);
    const float* Kv = K2 + v*HALFT*8;
    #pragma unroll
    for (int cb = 0; cb < 4; ++cb) {
      float a = Kv[2*cb], b = Kv[2*cb+1];
      re[cb] += a*c0r - b*c0i;
      im[cb] += a*c0i + b*c0r;
    }
    float d2r = dr*dr - di*di, d2i = 2.0f*dr*di;
    float ar = c0r*dr - c0i*di, ai = c0r*di + c0i*dr;
    float br = ar*dr - ai*di,  bi = ar*di + ai*dr;
    for (int i = 0; i < 95; ++i) {
      const float* ka = Kv + (2*i+1)*8;
      const float* kb = Kv + (2*i+2)*8;
      #pragma unroll
      for (int cb = 0; cb < 4; ++cb)
        re[cb] += ka[2*cb]*ar - ka[2*cb+1]*ai;
      #pragma unroll
      for (int cb = 0; cb < 4; ++cb)
        re[cb] += kb[2*cb]*br - kb[2*cb+1]*bi;
      rot(ar, ai, d2r, d2i);
      rot(br, bi, d2r, d2i);
    }
    {
      const float* ka = Kv + 191*8;
      #pragma unroll
      for (int cb = 0; cb < 4; ++cb)
        re[cb] += ka[2*cb]*ar - ka[2*cb+1]*ai;
    }
    const float* kd = Kv + 192*8;
    #pragma unroll
    for (int cb = 0; cb < 4; ++cb) { re[cb] += kd[2*cb]; im[cb] += kd[2*cb+1]; }
  }
  float* o = imgpart + (chunk*NPIX + pix)*8;
  #pragma unroll
  for (int cb = 0; cb < 4; ++cb) { o[2*cb] = re[cb]; o[2*cb+1] = im[cb]; }
}

__global__ __launch_bounds__(256) void out_fb_kernel(
    const float* __restrict__ imgpart, float* __restrict__ out, int nchunk) {
  const int pix = blockIdx.x*256 + threadIdx.x;
  float re[4] = {0,0,0,0}, im[4] = {0,0,0,0};
  for (int ch = 0; ch < nchunk; ++ch) {
    const float* p = imgpart + (ch*NPIX + pix)*8;
    #pragma unroll
    for (int cb = 0; cb < 4; ++cb) { re[cb] += p[2*cb]; im[cb] += p[2*cb+1]; }
  }
  #pragma unroll
  for (int b = 0; b < 2; ++b)
    #pragma unroll
    for (int c = 0; c < 2; ++c) {
      const int cb = b*2 + c;
      out[(b*NPIX + pix)*2 + c] = sqrtf(re[cb]*re[cb] + im[cb]*im[cb]);
    }
}

extern "C" void kernel_launch(void* const* d_in, const int* in_sizes, int n_in,
                              void* d_out, int out_size, void* d_ws, size_t ws_size,
                              hipStream_t stream) {
  const float* x       = (const float*)d_in[0];
  const float* points  = (const float*)d_in[1];
  const float* weights = (const float*)d_in[2];
  float* out = (float*)d_out;

  // byte layout (A never materialized: ws need drops to ~40.6MB)
  const size_t OFF_S = 21145088ull;  // BT/CxT/SxT/K2edge/kyv/Abuf/combos
  const size_t NEED  = OFF_S + 19464192ull;   // + partials = 40,609,280

  if (ws_size >= NEED) {
    char* wsb = (char*)d_ws;
    unsigned short* BT   = (unsigned short*)(wsb + 0);          //  9,732,096
    unsigned short* CxT  = (unsigned short*)(wsb + 9732096);    //  4,866,048
    unsigned short* SxT  = (unsigned short*)(wsb + 14598144);   //  4,866,048
    float* K2edge        = (float*)(wsb + 19464192);            //      8,192
    float* kyv           = (float*)(wsb + 19472384);            //     50,688
    float* Abuf          = (float*)(wsb + 19523072);            //    811,008
    float* combos        = (float*)(wsb + 20334080);            //    811,008
    char* S              = wsb + OFF_S;
    // phase A (dead after gemm1)
    unsigned short* Am   = (unsigned short*)(S + 0);            //  9,732,096
    unsigned short* XT   = (unsigned short*)(S + 9732096);      //    294,912
    // phase B (overlaps phase A; stream-ordered)
    float* partials      = (float*)(S + 0);                     // 19,464,192

    phase_kernel<<<dim3(65,25), 256, 0, stream>>>(points, x, BT, CxT, SxT, Am, XT, kyv);
    gemm1_kernel<<<792, 256, 0, stream>>>(Am, XT, kyv, Abuf);
    combine2_kernel<<<(M2P + 255)/256, 256, 0, stream>>>(
        Abuf, weights, combos, K2edge);
    adj_gemm<<<240, 256, 0, stream>>>(combos, CxT, SxT, BT, partials);
    finish_kernel<<<576, 256, 0, stream>>>(BT, CxT, SxT, K2edge, partials, out);
  } else {
    // r2 fallback path
    float* ws = (float*)d_ws;
    const size_t ws_floats = ws_size / sizeof(float);
    int nsplit = 16, nchunk = 16;
    auto need = [&](int ns, int nc) -> size_t {
      return (size_t)ns*196608 + 8 + 197632 + (size_t)nc*294912;
    };
    while (need(nsplit, nchunk) > ws_floats && nchunk > 1) nchunk >>= 1;
    while (need(nsplit, nchunk) > ws_floats && nsplit > 1) nsplit >>= 1;

    float* kpart   = ws;
    float* dcsum   = kpart + (size_t)nsplit*196608;
    float* K2      = dcsum + 8;
    float* imgpart = K2 + 197632;

    switch (nsplit) {
      case 16: fwd_kernel<12><<<dim3(NVIEWS,16), 192, 0, stream>>>(x, points, kpart); break;
      case 8:  fwd_kernel<24><<<dim3(NVIEWS,8),  192, 0, stream>>>(x, points, kpart); break;
      case 4:  fwd_kernel<48><<<dim3(NVIEWS,4),  192, 0, stream>>>(x, points, kpart); break;
      case 2:  fwd_kernel<96><<<dim3(NVIEWS,2),  192, 0, stream>>>(x, points, kpart); break;
      default: fwd_kernel<192><<<dim3(NVIEWS,1), 192, 0, stream>>>(x, points, kpart); break;
    }
    dc_kernel<<<1, 256, 0, stream>>>(x, dcsum);
    combine_kernel<<<(NVIEWS*HALFT + 255)/256, 256, 0, stream>>>(
        kpart, dcsum, weights, K2, nsplit);
    switch (nchunk) {
      case 16: adj_kernel<8>  <<<dim3(NPIX/256,16), 256, 0, stream>>>(K2, points, imgpart); break;
      case 8:  adj_kernel<16> <<<dim3(NPIX/256,8),  256, 0, stream>>>(K2, points, imgpart); break;
      case 4:  adj_kernel<32> <<<dim3(NPIX/256,4),  256, 0, stream>>>(K2, points, imgpart); break;
      case 2:  adj_kernel<64> <<<dim3(NPIX/256,2),  256, 0, stream>>>(K2, points, imgpart); break;
      default: adj_kernel<128><<<dim3(NPIX/256,1),  256, 0, stream>>>(K2, points, imgpart); break;
    }
    out_fb_kernel<<<NPIX/256, 256, 0, stream>>>(imgpart, out, nchunk);
  }
}

// Round 15
// 123.709 us; speedup vs baseline: 1.1665x; 1.1665x over previous
//
#include <hip/hip_runtime.h>
#include <math.h>

// KSpaceResampling: type-2 NUDFT -> ramp weights -> type-1 adjoint -> abs
// R15: revert to R12 (best, 124.5us) — fused-adj is dead (R8: XCD dup;
// R14: serial VALU chain at <1 wave/SIMD). One low-risk change on top:
// bf16 split-K partials (halves partials write+read, ~19.5MB saved).

#define HH 192
#define WW 192
#define NVIEWS 128
#define NSAMP 384
#define NPIX (HH*WW)      // 36864
#define HALFT 193         // stored t = 0..192
#define M2 12545          // 65 * 193  (v2 in [0,64])
#define M2P 12672         // padded
#define KTOT 25344        // 2 * M2P   (adjoint GEMM K: Cy-part ; Sy-part)
#define NSPLITK 33        // adjoint GEMM K-split (25344/33 = 768)

typedef __attribute__((ext_vector_type(8))) short bf16x8;
typedef __attribute__((ext_vector_type(4))) float f32x4;
typedef __attribute__((ext_vector_type(8))) unsigned short u16x8;

__device__ __forceinline__ void rot(float& cr, float& ci, float dr, float di) {
  float nr = cr*dr - ci*di;
  float ni = cr*di + ci*dr;
  cr = nr; ci = ni;
}
__device__ __forceinline__ unsigned short f2b(float f) {
  unsigned int u = __float_as_uint(f);
  u += 0x7fffu + ((u >> 16) & 1u);
  return (unsigned short)(u >> 16);
}
__device__ __forceinline__ float b2f(unsigned short h) {
  return __uint_as_float(((unsigned int)h) << 16);
}

// ---------------- phase tables + xprep + kyv (merged) ----------------
// role = blockIdx.y: [0,4) x-tables; [4,8) y-tables; 8 = xprep + kyv.
__global__ __launch_bounds__(256) void phase_kernel(
    const float* __restrict__ points, const float* __restrict__ x,
    unsigned short* __restrict__ BT, unsigned short* __restrict__ CxT,
    unsigned short* __restrict__ SxT, unsigned short* __restrict__ Am,
    unsigned short* __restrict__ XT, float* __restrict__ kyv) {
  const int v2 = blockIdx.x;
  const int role = blockIdx.y;
  const int t = threadIdx.x;
  if (role == 8) {
    for (int idx = v2*256 + t; idx < 768*192; idx += 65*256) {
      const int n = idx / 192, h = idx - n*192;
      const int cb = n / 192, w = n - cb*192;
      const int b = cb >> 1, c = cb & 1;
      XT[idx] = f2b(x[(((size_t)b*HH + h)*WW + w)*2 + c]);
    }
    for (int idx = v2*256 + t; idx < M2P; idx += 65*256) {
      if (idx < M2) {
        const int v2b = idx / HALFT, tb = idx - v2b*HALFT;
        kyv[idx] = points[(v2b*NSAMP + tb)*2 + 1];
      } else {
        kyv[idx] = 0.f;
      }
    }
    return;
  }
  if (t >= HALFT) return;
  if (role < 4) {
    const int hsplit = role;
    const float kx = points[(v2*NSAMP + t)*2 + 0];
    const int m2 = v2*HALFT + t;
    const int h0 = hsplit*48;
    float cr, ci; __sincosf(kx*(float)(h0-96), &ci, &cr);
    float dr, di; __sincosf(kx, &di, &dr);
    u16x8 pc, ps;
    for (int j = 0; j < 48; ++j) {
      const int h = h0 + j;
      CxT[(size_t)h*M2P + m2] = f2b(cr);
      SxT[(size_t)h*M2P + m2] = f2b(ci);
      pc[j&7] = f2b(cr); ps[j&7] = f2b(ci);
      if ((j&7) == 7) {
        *(u16x8*)(Am + (size_t)m2*192 + (h-7))         = pc;
        *(u16x8*)(Am + (size_t)(12672+m2)*192 + (h-7)) = ps;
      }
      rot(cr, ci, dr, di);
    }
  } else {
    const int wsplit = role - 4;
    const float ky = points[(v2*NSAMP + t)*2 + 1];
    const int kap = v2*HALFT + t;
    const int w0 = wsplit*48;
    float cr, ci; __sincosf(ky*(float)(w0-96), &ci, &cr);
    float dr, di; __sincosf(ky, &di, &dr);
    for (int j = 0; j < 48; ++j) {
      BT[(size_t)(w0+j)*KTOT + kap]       = f2b(cr);
      BT[(size_t)(w0+j)*KTOT + M2P + kap] = f2b(ci);
      rot(cr, ci, dr, di);
    }
  }
}

// ---------------- forward: fused gemm1 (+ w-phase contraction) ----------------

// XCD-swizzled 1D grid (792): idx = (L&7)*99 + (L>>3); mt = idx>>2; cb = idx&3.
__global__ __launch_bounds__(256) void gemm1_kernel(
    const unsigned short* __restrict__ Am, const unsigned short* __restrict__ XT,
    const float* __restrict__ kyv, float* __restrict__ Abuf) {
  __shared__ float lds[2][128][2];
  const int L = blockIdx.x;
  const int idx0 = (L & 7)*99 + (L >> 3);
  const int mt = idx0 >> 2;           // 0..197
  const int cb = idx0 & 3;            // 0..3
  const int wv = threadIdx.x >> 6;
  const int lane = threadIdx.x & 63;
  const int r = lane & 15, kg = lane >> 4;
  const int mhalf = wv >> 1;          // 0/1: m 64-half
  const int whalf = wv & 1;           // 0/1: w 96-half
  const int mbase = mt*128 + mhalf*64;
  const int wbase = whalf*96;
  const int nbase = cb*192 + wbase;

  f32x4 acc[4][6];
  #pragma unroll
  for (int a = 0; a < 4; ++a)
    #pragma unroll
    for (int b = 0; b < 6; ++b) acc[a][b] = (f32x4){0.f,0.f,0.f,0.f};

  const unsigned short* Ap = Am + (size_t)(mbase + r)*192 + kg*8;
  const unsigned short* Bp = XT + (size_t)(nbase + r)*192 + kg*8;
  #pragma unroll
  for (int ks = 0; ks < 6; ++ks) {
    bf16x8 af[4], bfr[6];
    #pragma unroll
    for (int mf = 0; mf < 4; ++mf)
      af[mf] = *(const bf16x8*)(Ap + (size_t)mf*16*192 + ks*32);
    #pragma unroll
    for (int nf = 0; nf < 6; ++nf)
      bfr[nf] = *(const bf16x8*)(Bp + (size_t)nf*16*192 + ks*32);
    #pragma unroll
    for (int mf = 0; mf < 4; ++mf)
      #pragma unroll
      for (int nf = 0; nf < 6; ++nf)
        acc[mf][nf] = __builtin_amdgcn_mfma_f32_16x16x32_bf16(
            af[mf], bfr[nf], acc[mf][nf], 0, 0, 0);
  }

  // in-register phase contraction over w
  const bool isCx = (mt < 99);
  const int m2w = mbase - (isCx ? 0 : 12672);
  float accA[16], accB[16];
  #pragma unroll
  for (int mf = 0; mf < 4; ++mf)
    #pragma unroll
    for (int reg = 0; reg < 4; ++reg) {
      const int m2 = m2w + mf*16 + kg*4 + reg;
      const float ky = kyv[m2];        // pad entries are 0 -> harmless
      float a0 = 0.f, b0 = 0.f;
      #pragma unroll
      for (int nf = 0; nf < 6; ++nf) {
        const float wo = (float)(wbase + nf*16 + r - 96);
        float sy, cy; __sincosf(ky*wo, &sy, &cy);
        const float g = acc[mf][nf][reg];
        a0 = fmaf(g, cy, a0);
        b0 = fmaf(g, sy, b0);
      }
      accA[mf*4+reg] = a0; accB[mf*4+reg] = b0;
    }
  #pragma unroll
  for (int msk = 1; msk <= 8; msk <<= 1) {
    #pragma unroll
    for (int i = 0; i < 16; ++i) {
      accA[i] += __shfl_xor(accA[i], msk);
      accB[i] += __shfl_xor(accB[i], msk);
    }
  }
  if (r == 0) {
    #pragma unroll
    for (int mf = 0; mf < 4; ++mf)
      #pragma unroll
      for (int reg = 0; reg < 4; ++reg) {
        const int mloc = mhalf*64 + mf*16 + kg*4 + reg;
        lds[whalf][mloc][0] = accA[mf*4+reg];
        lds[whalf][mloc][1] = accB[mf*4+reg];
      }
  }
  __syncthreads();
  {
    const int tid = threadIdx.x;
    const int mloc = tid >> 1, slot = tid & 1;
    const float val = lds[0][mloc][slot] + lds[1][mloc][slot];
    const int m2 = mt*128 + mloc - (isCx ? 0 : 12672);
    const int oidx = isCx ? (slot ? 3 : 0) : (slot ? 1 : 2);
    Abuf[((size_t)cb*M2P + m2)*4 + oidx] = val;
  }
}

// ---------------- adjoint: tmat (combine2 folded in) + GEMM -----------------

// blockIdx.y in [0,192): h-row of A; == 192: K2edge emission.
__global__ __launch_bounds__(256) void tmat_kernel(
    const float* __restrict__ Abuf, const float* __restrict__ weights,
    const unsigned short* __restrict__ CxT, const unsigned short* __restrict__ SxT,
    unsigned short* __restrict__ A, float* __restrict__ K2edge) {
  const int m2 = blockIdx.x*256 + threadIdx.x;
  if (m2 >= M2P) return;
  const int role = blockIdx.y;
  if (role == 192) {
    if (m2 >= M2) return;
    const int v2 = m2 / HALFT, t = m2 - v2*HALFT;
    if (t != 0 && t != 192) return;
    const float f = weights[t] * (1.0f/36864.0f);   // unpaired: no 2x
    const bool hp = (v2 >= 1 && v2 <= 63);
    const int d = (t == 0) ? 0 : 1;
    #pragma unroll
    for (int cb = 0; cb < 4; ++cb) {
      const float4 Av = *(const float4*)(Abuf + ((size_t)cb*M2P + m2)*4);
      const float A1 = Av.x, A2 = Av.y, A3 = Av.z, A4 = Av.w;
      float* e = K2edge + ((v2*2 + d)*4 + cb)*2;
      e[0] = f*(A1 - A2); e[1] = -f*(A3 + A4);
      if (hp) {
        float* e2 = K2edge + (((128 - v2)*2 + d)*4 + cb)*2;
        e2[0] = f*(A1 + A2); e2[1] = f*(A3 - A4);
      }
    }
    return;
  }
  const int h = role;
  if (m2 >= M2) {
    #pragma unroll
    for (int cb = 0; cb < 4; ++cb) {
      unsigned short* Arow = A + (size_t)(cb*192 + h)*KTOT;
      Arow[m2] = 0; Arow[M2P + m2] = 0;
    }
    return;
  }
  const int v2 = m2 / HALFT, t = m2 - v2*HALFT;
  float f = weights[t] * (1.0f/36864.0f);
  if (t != 0 && t != 192) f *= 2.0f;
  const bool hp = (v2 >= 1 && v2 <= 63);
  const float cx = b2f(CxT[(size_t)h*M2P + m2]);
  const float sx = b2f(SxT[(size_t)h*M2P + m2]);
  #pragma unroll
  for (int cb = 0; cb < 4; ++cb) {
    const float4 Av = *(const float4*)(Abuf + ((size_t)cb*M2P + m2)*4);
    const float A1 = Av.x, A2 = Av.y, A3 = Av.z, A4 = Av.w;
    float p0, p1, q0, q1;
    if (hp) {
      p0 = 2.f*f*A1; p1 = 2.f*f*A3; q0 = 2.f*f*A4; q1 = 2.f*f*A2;
    } else {
      const float kr = f*(A1 - A2), ki = -f*(A3 + A4);
      p0 = kr; p1 = -ki; q0 = -ki; q1 = -kr;
    }
    unsigned short* Arow = A + (size_t)(cb*192 + h)*KTOT;
    Arow[m2]       = f2b(p0*cx + p1*sx);
    Arow[M2P + m2] = f2b(q0*cx + q1*sx);
  }
}

// XCD-swizzled grid: 240 blocks; xcd = L&7, slot = L>>3, kc = (slot/6)*8 + xcd,
// mt = slot%6. The 6 same-kc blocks (sharing BT columns) land on one XCD.
// Partials stored as bf16 (halves write+read traffic; 33-way fp32 re-sum).
__global__ __launch_bounds__(256) void adj_gemm(
    const unsigned short* __restrict__ A, const unsigned short* __restrict__ BT,
    unsigned short* __restrict__ partials) {
  const int L = blockIdx.x;
  const int xcd = L & 7, slot = L >> 3;
  const int g = slot / 6;
  const int kc = g*8 + xcd;
  if (kc >= NSPLITK) return;
  const int mt = slot - g*6;
  const int wv = threadIdx.x >> 6;
  const int lane = threadIdx.x & 63;
  const int r = lane & 15, kg = lane >> 4;
  const int jbase = mt*128 + (wv>>1)*64;
  const int wbase = (wv&1)*96;
  const int kb = kc*768 + kg*8;

  f32x4 acc[4][6];
  #pragma unroll
  for (int a = 0; a < 4; ++a)
    #pragma unroll
    for (int b = 0; b < 6; ++b) acc[a][b] = (f32x4){0.f,0.f,0.f,0.f};

  const unsigned short* Ap = A + (size_t)(jbase + r)*KTOT + kb;
  const unsigned short* Bp = BT + (size_t)(wbase + r)*KTOT + kb;
  for (int ks = 0; ks < 24; ++ks) {
    bf16x8 af[4], bfr[6];
    #pragma unroll
    for (int mf = 0; mf < 4; ++mf)
      af[mf] = *(const bf16x8*)(Ap + (size_t)mf*16*KTOT + ks*32);
    #pragma unroll
    for (int nf = 0; nf < 6; ++nf)
      bfr[nf] = *(const bf16x8*)(Bp + (size_t)nf*16*KTOT + ks*32);
    #pragma unroll
    for (int mf = 0; mf < 4; ++mf)
      #pragma unroll
      for (int nf = 0; nf < 6; ++nf)
        acc[mf][nf] = __builtin_amdgcn_mfma_f32_16x16x32_bf16(
            af[mf], bfr[nf], acc[mf][nf], 0, 0, 0);
  }
  unsigned short* base = partials + (size_t)kc*147456;
  #pragma unroll
  for (int mf = 0; mf < 4; ++mf)
    #pragma unroll
    for (int nf = 0; nf < 6; ++nf) {
      const int w = wbase + nf*16 + r;
      const int j = jbase + mf*16 + kg*4;
      ushort4 u = make_ushort4(f2b(acc[mf][nf][0]), f2b(acc[mf][nf][1]),
                               f2b(acc[mf][nf][2]), f2b(acc[mf][nf][3]));
      *(ushort4*)(base + (size_t)w*768 + j) = u;
    }
}

// finish: im (t=0 unpaired samples only) + partials K-reduction + magnitude.
__global__ __launch_bounds__(256) void finish_kernel(
    const unsigned short* __restrict__ BT, const unsigned short* __restrict__ CxT,
    const unsigned short* __restrict__ SxT, const float* __restrict__ K2edge,
    const unsigned short* __restrict__ partials, float* __restrict__ out) {
  __shared__ float cxs[65][8], sxs[65][8], cys[65][8], sys[65][8];
  __shared__ float redI[4][64][4], redR[4][64][4];
  const int bx = blockIdx.x;
  const int h0 = (bx/24)*8, w0 = (bx%24)*8;
  const int tid = threadIdx.x;
  for (int i = tid; i < 65*8; i += 256) {
    const int v2 = i >> 3, e = i & 7;
    const int kap = v2*HALFT;           // t = 0
    cxs[v2][e] = b2f(CxT[(size_t)(h0+e)*M2P + kap]);
    sxs[v2][e] = b2f(SxT[(size_t)(h0+e)*M2P + kap]);
    cys[v2][e] = b2f(BT[(size_t)(w0+e)*KTOT + kap]);
    sys[v2][e] = b2f(BT[(size_t)(w0+e)*KTOT + M2P + kap]);
  }
  __syncthreads();
  const int g = tid >> 6, hi = (tid >> 3) & 7, wi = tid & 7;
  const int h = h0 + hi, w = w0 + wi;
  float im[4] = {0,0,0,0};
  for (int v = g*32; v < g*32 + 32; ++v) {
    const int v2 = (v <= 64) ? v : 128 - v;
    const float sg = (v <= 64) ? 1.f : -1.f;
    const float cx = cxs[v2][hi], sx = sg*sxs[v2][hi];
    const float cy = cys[v2][wi], sy = sys[v2][wi];
    const float t1 = cx*sy + sx*cy;
    const float t2 = cx*cy - sx*sy;
    const int idx = v*16;
    #pragma unroll
    for (int cb = 0; cb < 4; ++cb)
      im[cb] += K2edge[idx + cb*2]*t1 + K2edge[idx + cb*2 + 1]*t2;
  }
  float re[4] = {0,0,0,0};
  for (int kc = g; kc < NSPLITK; kc += 4) {
    const unsigned short* p = partials + (size_t)kc*147456 + (size_t)w*768;
    #pragma unroll
    for (int cb = 0; cb < 4; ++cb)
      re[cb] += b2f(p[cb*192 + h]);
  }
  const int p = tid & 63;
  #pragma unroll
  for (int cb = 0; cb < 4; ++cb) { redI[g][p][cb] = im[cb]; redR[g][p][cb] = re[cb]; }
  __syncthreads();
  if (g == 0) {
    #pragma unroll
    for (int cb = 0; cb < 4; ++cb) {
      im[cb] += redI[1][p][cb] + redI[2][p][cb] + redI[3][p][cb];
      re[cb] += redR[1][p][cb] + redR[2][p][cb] + redR[3][p][cb];
    }
    const int pix = h*192 + w;
    #pragma unroll
    for (int b = 0; b < 2; ++b)
      #pragma unroll
      for (int c = 0; c < 2; ++c) {
        const int cb = b*2 + c;
        out[((size_t)b*NPIX + pix)*2 + c] = sqrtf(re[cb]*re[cb] + im[cb]*im[cb]);
      }
  }
}

// ---------------- fallback (r2, validated) ----------------

template <int HPER>
__global__ __launch_bounds__(192) void fwd_kernel(
    const float* __restrict__ x, const float* __restrict__ points,
    float* __restrict__ kpart) {
  const int v = blockIdx.x;
  const int split = blockIdx.y;
  const int t = threadIdx.x;
  const int m = v*NSAMP + t;
  const float kx = points[2*m+0];
  const float ky = points[2*m+1];
  const int h0 = split*HPER;

  float kr[4] = {0,0,0,0}, ki[4] = {0,0,0,0};
  float cyr, cyi; __sincosf(96.0f*ky, &cyi, &cyr);
  float dyr, dyi; __sincosf(-ky, &dyi, &dyr);
  float cx0r, cx0i; __sincosf(kx*(float)(96-h0), &cx0i, &cx0r);
  float dxr, dxi; __sincosf(-kx, &dxi, &dxr);

  for (int wp = 0; wp < 96; ++wp) {
    const int w0 = wp*2;
    float g0r[4]={0,0,0,0}, g0i[4]={0,0,0,0};
    float g1r[4]={0,0,0,0}, g1i[4]={0,0,0,0};
    float cxr = cx0r, cxi = cx0i;
    const float* p0 = x + (h0*WW + w0)*2;
    const float* p1 = p0 + HH*WW*2;
    #pragma unroll 4
    for (int h = 0; h < HPER; ++h) {
      float4 a = *(const float4*)(p0 + h*(WW*2));
      float4 b = *(const float4*)(p1 + h*(WW*2));
      g0r[0] += a.x*cxr; g0i[0] += a.x*cxi;
      g0r[1] += a.y*cxr; g0i[1] += a.y*cxi;
      g1r[0] += a.z*cxr; g1i[0] += a.z*cxi;
      g1r[1] += a.w*cxr; g1i[1] += a.w*cxi;
      g0r[2] += b.x*cxr; g0i[2] += b.x*cxi;
      g0r[3] += b.y*cxr; g0i[3] += b.y*cxi;
      g1r[2] += b.z*cxr; g1i[2] += b.z*cxi;
      g1r[3] += b.w*cxr; g1i[3] += b.w*cxi;
      rot(cxr, cxi, dxr, dxi);
    }
    #pragma unroll
    for (int cb = 0; cb < 4; ++cb) {
      kr[cb] += g0r[cb]*cyr - g0i[cb]*cyi;
      ki[cb] += g0r[cb]*cyi + g0i[cb]*cyr;
    }
    rot(cyr, cyi, dyr, dyi);
    #pragma unroll
    for (int cb = 0; cb < 4; ++cb) {
      kr[cb] += g1r[cb]*cyr - g1i[cb]*cyi;
      ki[cb] += g1r[cb]*cyi + g1i[cb]*cyr;
    }
    rot(cyr, cyi, dyr, dyi);
  }
  float* o = kpart + (((split*NVIEWS + v)*192 + t)*4)*2;
  #pragma unroll
  for (int cb = 0; cb < 4; ++cb) { o[2*cb] = kr[cb]; o[2*cb+1] = ki[cb]; }
}

__global__ __launch_bounds__(256) void dc_kernel(
    const float* __restrict__ x, float* __restrict__ dcsum) {
  const int tid = threadIdx.x;
  float s0=0.f, s1=0.f, s2=0.f, s3=0.f;
  for (int i = tid; i < NPIX; i += 256) {
    float2 a = *(const float2*)(x + i*2);
    float2 b = *(const float2*)(x + HH*WW*2 + i*2);
    s0 += a.x; s1 += a.y; s2 += b.x; s3 += b.y;
  }
  #pragma unroll
  for (int off = 32; off > 0; off >>= 1) {
    s0 += __shfl_down(s0, off);
    s1 += __shfl_down(s1, off);
    s2 += __shfl_down(s2, off);
    s3 += __shfl_down(s3, off);
  }
  __shared__ float red[4][4];
  const int wv = tid >> 6, ln = tid & 63;
  if (ln == 0) { red[0][wv]=s0; red[1][wv]=s1; red[2][wv]=s2; red[3][wv]=s3; }
  __syncthreads();
  if (tid < 4) {
    float tot = red[tid][0]+red[tid][1]+red[tid][2]+red[tid][3];
    dcsum[2*tid] = tot; dcsum[2*tid+1] = 0.0f;
  }
}

__global__ __launch_bounds__(256) void combine_kernel(
    const float* __restrict__ kpart, const float* __restrict__ dcsum,
    const float* __restrict__ weights, float* __restrict__ K2, int nsplit) {
  const int idx = blockIdx.x*256 + threadIdx.x;
  if (idx >= NVIEWS*HALFT) return;
  const int v = idx / HALFT, t = idx % HALFT;
  float f = weights[t] * (1.0f/36864.0f);
  if (t != 0 && t != 192) f *= 2.0f;
  float o[8];
  if (t == 192) {
    #pragma unroll
    for (int cb = 0; cb < 4; ++cb) { o[2*cb] = f*dcsum[2*cb]; o[2*cb+1] = f*dcsum[2*cb+1]; }
  } else {
    #pragma unroll
    for (int cb = 0; cb < 4; ++cb) {
      float ar = 0.f, ai = 0.f;
      for (int s = 0; s < nsplit; ++s) {
        const float* p = kpart + (((s*NVIEWS + v)*192 + t)*4 + cb)*2;
        ar += p[0]; ai += p[1];
      }
      o[2*cb] = f*ar; o[2*cb+1] = f*ai;
    }
  }
  float* q = K2 + idx*8;
  #pragma unroll
  for (int j = 0; j < 8; ++j) q[j] = o[j];
}

template <int VPC>
__global__ __launch_bounds__(256) void adj_kernel(
    const float* __restrict__ K2, const float* __restrict__ points,
    float* __restrict__ imgpart) {
  const int pix = blockIdx.x*256 + threadIdx.x;
  const int chunk = blockIdx.y;
  const float nh = (float)(pix / WW - 96);
  const float nw = (float)(pix % WW - 96);
  float re[4] = {0,0,0,0}, im[4] = {0,0,0,0};
  const float INVPI = 0.3183098861837907f;
  const float PI192 = 3.14159265358979f / 192.0f;
  for (int v = chunk*VPC; v < chunk*VPC + VPC; ++v) {
    const float ct = -points[2*(v*NSAMP)+0] * INVPI;
    const float st = -points[2*(v*NSAMP)+1] * INVPI;
    const float alpha = ct*nh + st*nw;
    const float delta = alpha * PI192;
    float dr, di; __sincosf(delta, &di, &dr);
    float c0r, c0i; __sincosf(-192.0f*delta, &c0i, &c0r);
    const float* Kv = K2 + v*HALFT*8;
    #pragma unroll
    for (int cb = 0; cb < 4; ++cb) {
      float a = Kv[2*cb], b = Kv[2*cb+1];
      re[cb] += a*c0r - b*c0i;
      im[cb] += a*c0i + b*c0r;
    }
    float d2r = dr*dr - di*di, d2i = 2.0f*dr*di;
    float ar = c0r*dr - c0i*di, ai = c0r*di + c0i*dr;
    float br = ar*dr - ai*di,  bi = ar*di + ai*dr;
    for (int i = 0; i < 95; ++i) {
      const float* ka = Kv + (2*i+1)*8;
      const float* kb = Kv + (2*i+2)*8;
      #pragma unroll
      for (int cb = 0; cb < 4; ++cb)
        re[cb] += ka[2*cb]*ar - ka[2*cb+1]*ai;
      #pragma unroll
      for (int cb = 0; cb < 4; ++cb)
        re[cb] += kb[2*cb]*br - kb[2*cb+1]*bi;
      rot(ar, ai, d2r, d2i);
      rot(br, bi, d2r, d2i);
    }
    {
      const float* ka = Kv + 191*8;
      #pragma unroll
      for (int cb = 0; cb < 4; ++cb)
        re[cb] += ka[2*cb]*ar - ka[2*cb+1]*ai;
    }
    const float* kd = Kv + 192*8;
    #pragma unroll
    for (int cb = 0; cb < 4; ++cb) { re[cb] += kd[2*cb]; im[cb] += kd[2*cb+1]; }
  }
  float* o = imgpart + (chunk*NPIX + pix)*8;
  #pragma unroll
  for (int cb = 0; cb < 4; ++cb) { o[2*cb] = re[cb]; o[2*cb+1] = im[cb]; }
}

__global__ __launch_bounds__(256) void out_fb_kernel(
    const float* __restrict__ imgpart, float* __restrict__ out, int nchunk) {
  const int pix = blockIdx.x*256 + threadIdx.x;
  float re[4] = {0,0,0,0}, im[4] = {0,0,0,0};
  for (int ch = 0; ch < nchunk; ++ch) {
    const float* p = imgpart + (ch*NPIX + pix)*8;
    #pragma unroll
    for (int cb = 0; cb < 4; ++cb) { re[cb] += p[2*cb]; im[cb] += p[2*cb+1]; }
  }
  #pragma unroll
  for (int b = 0; b < 2; ++b)
    #pragma unroll
    for (int c = 0; c < 2; ++c) {
      const int cb = b*2 + c;
      out[(b*NPIX + pix)*2 + c] = sqrtf(re[cb]*re[cb] + im[cb]*im[cb]);
    }
}

extern "C" void kernel_launch(void* const* d_in, const int* in_sizes, int n_in,
                              void* d_out, int out_size, void* d_ws, size_t ws_size,
                              hipStream_t stream) {
  const float* x       = (const float*)d_in[0];
  const float* points  = (const float*)d_in[1];
  const float* weights = (const float*)d_in[2];
  float* out = (float*)d_out;

  // byte layout
  const size_t OFF_S   = 20334080ull;   // BT/CxT/SxT/K2edge/kyv/Abuf before S
  const size_t SZ_AADJ = 38928384ull;
  const size_t NEED    = OFF_S + SZ_AADJ + 9732096ull;  // + bf16 partials

  if (ws_size >= NEED) {
    char* wsb = (char*)d_ws;
    unsigned short* BT   = (unsigned short*)(wsb + 0);          //  9,732,096
    unsigned short* CxT  = (unsigned short*)(wsb + 9732096);    //  4,866,048
    unsigned short* SxT  = (unsigned short*)(wsb + 14598144);   //  4,866,048
    float* K2edge        = (float*)(wsb + 19464192);            //      8,192
    float* kyv           = (float*)(wsb + 19472384);            //     50,688
    float* Abuf          = (float*)(wsb + 19523072);            //    811,008
    char* S              = wsb + OFF_S;
    // phase A (dead after gemm1)
    unsigned short* Am   = (unsigned short*)(S + 0);            //  9,732,096
    unsigned short* XT   = (unsigned short*)(S + 9732096);      //    294,912
    // phase B (overlaps phase A; stream-ordered)
    unsigned short* Aadj = (unsigned short*)(S + 0);            // 38,928,384
    unsigned short* partials = (unsigned short*)(S + SZ_AADJ);  //  9,732,096

    phase_kernel<<<dim3(65,9), 256, 0, stream>>>(points, x, BT, CxT, SxT, Am, XT, kyv);
    gemm1_kernel<<<792, 256, 0, stream>>>(Am, XT, kyv, Abuf);
    tmat_kernel<<<dim3((M2P + 255)/256, 193), 256, 0, stream>>>(
        Abuf, weights, CxT, SxT, Aadj, K2edge);
    adj_gemm<<<240, 256, 0, stream>>>(Aadj, BT, partials);
    finish_kernel<<<576, 256, 0, stream>>>(BT, CxT, SxT, K2edge, partials, out);
  } else {
    // r2 fallback path
    float* ws = (float*)d_ws;
    const size_t ws_floats = ws_size / sizeof(float);
    int nsplit = 16, nchunk = 16;
    auto need = [&](int ns, int nc) -> size_t {
      return (size_t)ns*196608 + 8 + 197632 + (size_t)nc*294912;
    };
    while (need(nsplit, nchunk) > ws_floats && nchunk > 1) nchunk >>= 1;
    while (need(nsplit, nchunk) > ws_floats && nsplit > 1) nsplit >>= 1;

    float* kpart   = ws;
    float* dcsum   = kpart + (size_t)nsplit*196608;
    float* K2      = dcsum + 8;
    float* imgpart = K2 + 197632;

    switch (nsplit) {
      case 16: fwd_kernel<12><<<dim3(NVIEWS,16), 192, 0, stream>>>(x, points, kpart); break;
      case 8:  fwd_kernel<24><<<dim3(NVIEWS,8),  192, 0, stream>>>(x, points, kpart); break;
      case 4:  fwd_kernel<48><<<dim3(NVIEWS,4),  192, 0, stream>>>(x, points, kpart); break;
      case 2:  fwd_kernel<96><<<dim3(NVIEWS,2),  192, 0, stream>>>(x, points, kpart); break;
      default: fwd_kernel<192><<<dim3(NVIEWS,1), 192, 0, stream>>>(x, points, kpart); break;
    }
    dc_kernel<<<1, 256, 0, stream>>>(x, dcsum);
    combine_kernel<<<(NVIEWS*HALFT + 255)/256, 256, 0, stream>>>(
        kpart, dcsum, weights, K2, nsplit);
    switch (nchunk) {
      case 16: adj_kernel<8>  <<<dim3(NPIX/256,16), 256, 0, stream>>>(K2, points, imgpart); break;
      case 8:  adj_kernel<16> <<<dim3(NPIX/256,8),  256, 0, stream>>>(K2, points, imgpart); break;
      case 4:  adj_kernel<32> <<<dim3(NPIX/256,4),  256, 0, stream>>>(K2, points, imgpart); break;
      case 2:  adj_kernel<64> <<<dim3(NPIX/256,2),  256, 0, stream>>>(K2, points, imgpart); break;
      default: adj_kernel<128><<<dim3(NPIX/256,1),  256, 0, stream>>>(K2, points, imgpart); break;
    }
    out_fb_kernel<<<NPIX/256, 256, 0, stream>>>(imgpart, out, nchunk);
  }
}

// Round 16
// 123.631 us; speedup vs baseline: 1.1672x; 1.0006x over previous
//
#include <hip/hip_runtime.h>
#include <hip/hip_cooperative_groups.h>
#include <math.h>

// KSpaceResampling: type-2 NUDFT -> ramp weights -> type-1 adjoint -> abs
// R16: cooperative mega-kernel — all 5 phases (tables / gemm1 / tmat /
// adj_gemm / finish) in ONE launch with 4 grid.sync()s, killing 4 launch
// boundaries. Phase bodies verbatim R15 (bit-identical). Falls back to the
// validated R15 5-kernel path if cooperative launch is unavailable/fails.

#define HH 192
#define WW 192
#define NVIEWS 128
#define NSAMP 384
#define NPIX (HH*WW)      // 36864
#define HALFT 193         // stored t = 0..192
#define M2 12545          // 65 * 193  (v2 in [0,64])
#define M2P 12672         // padded
#define KTOT 25344        // 2 * M2P   (adjoint GEMM K: Cy-part ; Sy-part)
#define NSPLITK 33        // adjoint GEMM K-split (25344/33 = 768)

typedef __attribute__((ext_vector_type(8))) short bf16x8;
typedef __attribute__((ext_vector_type(4))) float f32x4;
typedef __attribute__((ext_vector_type(8))) unsigned short u16x8;

__device__ __forceinline__ void rot(float& cr, float& ci, float dr, float di) {
  float nr = cr*dr - ci*di;
  float ni = cr*di + ci*dr;
  cr = nr; ci = ni;
}
__device__ __forceinline__ unsigned short f2b(float f) {
  unsigned int u = __float_as_uint(f);
  u += 0x7fffu + ((u >> 16) & 1u);
  return (unsigned short)(u >> 16);
}
__device__ __forceinline__ float b2f(unsigned short h) {
  return __uint_as_float(((unsigned int)h) << 16);
}

// ======================= cooperative mega-kernel ============================
__global__ void __launch_bounds__(256) mega_kernel(
    const float* __restrict__ points, const float* __restrict__ x,
    const float* __restrict__ weights,
    unsigned short* __restrict__ BT, unsigned short* __restrict__ CxT,
    unsigned short* __restrict__ SxT, unsigned short* __restrict__ Am,
    unsigned short* __restrict__ XT, float* __restrict__ kyv,
    float* __restrict__ Abuf, unsigned short* __restrict__ Aadj,
    float* __restrict__ K2edge, unsigned short* __restrict__ partials,
    float* __restrict__ out) {
  cooperative_groups::grid_group grid = cooperative_groups::this_grid();
  const int G = gridDim.x;
  const int bid = blockIdx.x;
  const int tid = threadIdx.x;

  __shared__ float lds1[2][128][2];
  __shared__ float cxs[65][8], sxs[65][8], cys[65][8], sys[65][8];
  __shared__ float redI[4][64][4], redR[4][64][4];

  // -------- phase 1: phase tables + xprep + kyv (585 units) --------
  for (int u = bid; u < 585; u += G) {
    const int v2 = u % 65;
    const int role = u / 65;
    if (role == 8) {
      for (int idx = v2*256 + tid; idx < 768*192; idx += 65*256) {
        const int n = idx / 192, h = idx - n*192;
        const int cb = n / 192, w = n - cb*192;
        const int b = cb >> 1, c = cb & 1;
        XT[idx] = f2b(x[(((size_t)b*HH + h)*WW + w)*2 + c]);
      }
      for (int idx = v2*256 + tid; idx < M2P; idx += 65*256) {
        if (idx < M2) {
          const int v2b = idx / HALFT, tb = idx - v2b*HALFT;
          kyv[idx] = points[(v2b*NSAMP + tb)*2 + 1];
        } else {
          kyv[idx] = 0.f;
        }
      }
    } else if (tid < HALFT) {
      if (role < 4) {
        const int hsplit = role;
        const float kx = points[(v2*NSAMP + tid)*2 + 0];
        const int m2 = v2*HALFT + tid;
        const int h0 = hsplit*48;
        float cr, ci; __sincosf(kx*(float)(h0-96), &ci, &cr);
        float dr, di; __sincosf(kx, &di, &dr);
        u16x8 pc, ps;
        for (int j = 0; j < 48; ++j) {
          const int h = h0 + j;
          CxT[(size_t)h*M2P + m2] = f2b(cr);
          SxT[(size_t)h*M2P + m2] = f2b(ci);
          pc[j&7] = f2b(cr); ps[j&7] = f2b(ci);
          if ((j&7) == 7) {
            *(u16x8*)(Am + (size_t)m2*192 + (h-7))         = pc;
            *(u16x8*)(Am + (size_t)(12672+m2)*192 + (h-7)) = ps;
          }
          rot(cr, ci, dr, di);
        }
      } else {
        const int wsplit = role - 4;
        const float ky = points[(v2*NSAMP + tid)*2 + 1];
        const int kap = v2*HALFT + tid;
        const int w0 = wsplit*48;
        float cr, ci; __sincosf(ky*(float)(w0-96), &ci, &cr);
        float dr, di; __sincosf(ky, &di, &dr);
        for (int j = 0; j < 48; ++j) {
          BT[(size_t)(w0+j)*KTOT + kap]       = f2b(cr);
          BT[(size_t)(w0+j)*KTOT + M2P + kap] = f2b(ci);
          rot(cr, ci, dr, di);
        }
      }
    }
  }
  __threadfence();
  grid.sync();

  // -------- phase 2: gemm1 + w-contraction (792 units) --------
  for (int L = bid; L < 792; L += G) {
    const int idx0 = (L & 7)*99 + (L >> 3);
    const int mt = idx0 >> 2;
    const int cb = idx0 & 3;
    const int wv = tid >> 6;
    const int lane = tid & 63;
    const int r = lane & 15, kg = lane >> 4;
    const int mhalf = wv >> 1;
    const int whalf = wv & 1;
    const int mbase = mt*128 + mhalf*64;
    const int wbase = whalf*96;
    const int nbase = cb*192 + wbase;

    f32x4 acc[4][6];
    #pragma unroll
    for (int a = 0; a < 4; ++a)
      #pragma unroll
      for (int b = 0; b < 6; ++b) acc[a][b] = (f32x4){0.f,0.f,0.f,0.f};

    const unsigned short* Ap = Am + (size_t)(mbase + r)*192 + kg*8;
    const unsigned short* Bp = XT + (size_t)(nbase + r)*192 + kg*8;
    #pragma unroll
    for (int ks = 0; ks < 6; ++ks) {
      bf16x8 af[4], bfr[6];
      #pragma unroll
      for (int mf = 0; mf < 4; ++mf)
        af[mf] = *(const bf16x8*)(Ap + (size_t)mf*16*192 + ks*32);
      #pragma unroll
      for (int nf = 0; nf < 6; ++nf)
        bfr[nf] = *(const bf16x8*)(Bp + (size_t)nf*16*192 + ks*32);
      #pragma unroll
      for (int mf = 0; mf < 4; ++mf)
        #pragma unroll
        for (int nf = 0; nf < 6; ++nf)
          acc[mf][nf] = __builtin_amdgcn_mfma_f32_16x16x32_bf16(
              af[mf], bfr[nf], acc[mf][nf], 0, 0, 0);
    }

    const bool isCx = (mt < 99);
    const int m2w = mbase - (isCx ? 0 : 12672);
    float accA[16], accB[16];
    #pragma unroll
    for (int mf = 0; mf < 4; ++mf)
      #pragma unroll
      for (int reg = 0; reg < 4; ++reg) {
        const int m2 = m2w + mf*16 + kg*4 + reg;
        const float ky = kyv[m2];
        float a0 = 0.f, b0 = 0.f;
        #pragma unroll
        for (int nf = 0; nf < 6; ++nf) {
          const float wo = (float)(wbase + nf*16 + r - 96);
          float sy, cy; __sincosf(ky*wo, &sy, &cy);
          const float g = acc[mf][nf][reg];
          a0 = fmaf(g, cy, a0);
          b0 = fmaf(g, sy, b0);
        }
        accA[mf*4+reg] = a0; accB[mf*4+reg] = b0;
      }
    #pragma unroll
    for (int msk = 1; msk <= 8; msk <<= 1) {
      #pragma unroll
      for (int i = 0; i < 16; ++i) {
        accA[i] += __shfl_xor(accA[i], msk);
        accB[i] += __shfl_xor(accB[i], msk);
      }
    }
    if (r == 0) {
      #pragma unroll
      for (int mf = 0; mf < 4; ++mf)
        #pragma unroll
        for (int reg = 0; reg < 4; ++reg) {
          const int mloc = mhalf*64 + mf*16 + kg*4 + reg;
          lds1[whalf][mloc][0] = accA[mf*4+reg];
          lds1[whalf][mloc][1] = accB[mf*4+reg];
        }
    }
    __syncthreads();
    {
      const int mloc = tid >> 1, slot = tid & 1;
      const float val = lds1[0][mloc][slot] + lds1[1][mloc][slot];
      const int m2 = mt*128 + mloc - (isCx ? 0 : 12672);
      const int oidx = isCx ? (slot ? 3 : 0) : (slot ? 1 : 2);
      Abuf[((size_t)cb*M2P + m2)*4 + oidx] = val;
    }
    __syncthreads();
  }
  __threadfence();
  grid.sync();

  // -------- phase 3: tmat (+K2edge), 50*193 = 9650 units --------
  for (int u = bid; u < 50*193; u += G) {
    const int mb = u % 50;
    const int role = u / 50;
    const int m2 = mb*256 + tid;
    if (m2 < M2P) {
      if (role == 192) {
        if (m2 < M2) {
          const int v2 = m2 / HALFT, t = m2 - v2*HALFT;
          if (t == 0 || t == 192) {
            const float f = weights[t] * (1.0f/36864.0f);
            const bool hp = (v2 >= 1 && v2 <= 63);
            const int d = (t == 0) ? 0 : 1;
            #pragma unroll
            for (int cb = 0; cb < 4; ++cb) {
              const float4 Av = *(const float4*)(Abuf + ((size_t)cb*M2P + m2)*4);
              const float A1 = Av.x, A2 = Av.y, A3 = Av.z, A4 = Av.w;
              float* e = K2edge + ((v2*2 + d)*4 + cb)*2;
              e[0] = f*(A1 - A2); e[1] = -f*(A3 + A4);
              if (hp) {
                float* e2 = K2edge + (((128 - v2)*2 + d)*4 + cb)*2;
                e2[0] = f*(A1 + A2); e2[1] = f*(A3 - A4);
              }
            }
          }
        }
      } else {
        const int h = role;
        if (m2 >= M2) {
          #pragma unroll
          for (int cb = 0; cb < 4; ++cb) {
            unsigned short* Arow = Aadj + (size_t)(cb*192 + h)*KTOT;
            Arow[m2] = 0; Arow[M2P + m2] = 0;
          }
        } else {
          const int v2 = m2 / HALFT, t = m2 - v2*HALFT;
          float f = weights[t] * (1.0f/36864.0f);
          if (t != 0 && t != 192) f *= 2.0f;
          const bool hp = (v2 >= 1 && v2 <= 63);
          const float cx = b2f(CxT[(size_t)h*M2P + m2]);
          const float sx = b2f(SxT[(size_t)h*M2P + m2]);
          #pragma unroll
          for (int cb = 0; cb < 4; ++cb) {
            const float4 Av = *(const float4*)(Abuf + ((size_t)cb*M2P + m2)*4);
            const float A1 = Av.x, A2 = Av.y, A3 = Av.z, A4 = Av.w;
            float p0, p1, q0, q1;
            if (hp) {
              p0 = 2.f*f*A1; p1 = 2.f*f*A3; q0 = 2.f*f*A4; q1 = 2.f*f*A2;
            } else {
              const float kr = f*(A1 - A2), ki = -f*(A3 + A4);
              p0 = kr; p1 = -ki; q0 = -ki; q1 = -kr;
            }
            unsigned short* Arow = Aadj + (size_t)(cb*192 + h)*KTOT;
            Arow[m2]       = f2b(p0*cx + p1*sx);
            Arow[M2P + m2] = f2b(q0*cx + q1*sx);
          }
        }
      }
    }
  }
  __threadfence();
  grid.sync();

  // -------- phase 4: adj_gemm, 240 units, bf16 partials --------
  for (int L = bid; L < 240; L += G) {
    const int xcd = L & 7, slot = L >> 3;
    const int g = slot / 6;
    const int kc = g*8 + xcd;
    if (kc < NSPLITK) {
      const int mt = slot - g*6;
      const int wv = tid >> 6;
      const int lane = tid & 63;
      const int r = lane & 15, kg = lane >> 4;
      const int jbase = mt*128 + (wv>>1)*64;
      const int wbase = (wv&1)*96;
      const int kb = kc*768 + kg*8;

      f32x4 acc[4][6];
      #pragma unroll
      for (int a = 0; a < 4; ++a)
        #pragma unroll
        for (int b = 0; b < 6; ++b) acc[a][b] = (f32x4){0.f,0.f,0.f,0.f};

      const unsigned short* Ap = Aadj + (size_t)(jbase + r)*KTOT + kb;
      const unsigned short* Bp = BT + (size_t)(wbase + r)*KTOT + kb;
      for (int ks = 0; ks < 24; ++ks) {
        bf16x8 af[4], bfr[6];
        #pragma unroll
        for (int mf = 0; mf < 4; ++mf)
          af[mf] = *(const bf16x8*)(Ap + (size_t)mf*16*KTOT + ks*32);
        #pragma unroll
        for (int nf = 0; nf < 6; ++nf)
          bfr[nf] = *(const bf16x8*)(Bp + (size_t)nf*16*KTOT + ks*32);
        #pragma unroll
        for (int mf = 0; mf < 4; ++mf)
          #pragma unroll
          for (int nf = 0; nf < 6; ++nf)
            acc[mf][nf] = __builtin_amdgcn_mfma_f32_16x16x32_bf16(
                af[mf], bfr[nf], acc[mf][nf], 0, 0, 0);
      }
      unsigned short* base = partials + (size_t)kc*147456;
      #pragma unroll
      for (int mf = 0; mf < 4; ++mf)
        #pragma unroll
        for (int nf = 0; nf < 6; ++nf) {
          const int w = wbase + nf*16 + r;
          const int j = jbase + mf*16 + kg*4;
          ushort4 uu = make_ushort4(f2b(acc[mf][nf][0]), f2b(acc[mf][nf][1]),
                                    f2b(acc[mf][nf][2]), f2b(acc[mf][nf][3]));
          *(ushort4*)(base + (size_t)w*768 + j) = uu;
        }
    }
  }
  __threadfence();
  grid.sync();

  // -------- phase 5: finish (576 tiles) --------
  for (int u = bid; u < 576; u += G) {
    const int h0 = (u/24)*8, w0 = (u%24)*8;
    for (int i = tid; i < 65*8; i += 256) {
      const int v2 = i >> 3, e = i & 7;
      const int kap = v2*HALFT;
      cxs[v2][e] = b2f(CxT[(size_t)(h0+e)*M2P + kap]);
      sxs[v2][e] = b2f(SxT[(size_t)(h0+e)*M2P + kap]);
      cys[v2][e] = b2f(BT[(size_t)(w0+e)*KTOT + kap]);
      sys[v2][e] = b2f(BT[(size_t)(w0+e)*KTOT + M2P + kap]);
    }
    __syncthreads();
    const int g = tid >> 6, hi = (tid >> 3) & 7, wi = tid & 7;
    const int h = h0 + hi, w = w0 + wi;
    float im[4] = {0,0,0,0};
    for (int v = g*32; v < g*32 + 32; ++v) {
      const int v2 = (v <= 64) ? v : 128 - v;
      const float sg = (v <= 64) ? 1.f : -1.f;
      const float cx = cxs[v2][hi], sx = sg*sxs[v2][hi];
      const float cy = cys[v2][wi], sy = sys[v2][wi];
      const float t1 = cx*sy + sx*cy;
      const float t2 = cx*cy - sx*sy;
      const int idx = v*16;
      #pragma unroll
      for (int cb = 0; cb < 4; ++cb)
        im[cb] += K2edge[idx + cb*2]*t1 + K2edge[idx + cb*2 + 1]*t2;
    }
    float re[4] = {0,0,0,0};
    for (int kc = g; kc < NSPLITK; kc += 4) {
      const unsigned short* p = partials + (size_t)kc*147456 + (size_t)w*768;
      #pragma unroll
      for (int cb = 0; cb < 4; ++cb)
        re[cb] += b2f(p[cb*192 + h]);
    }
    const int p = tid & 63;
    #pragma unroll
    for (int cb = 0; cb < 4; ++cb) { redI[g][p][cb] = im[cb]; redR[g][p][cb] = re[cb]; }
    __syncthreads();
    if (g == 0) {
      #pragma unroll
      for (int cb = 0; cb < 4; ++cb) {
        im[cb] += redI[1][p][cb] + redI[2][p][cb] + redI[3][p][cb];
        re[cb] += redR[1][p][cb] + redR[2][p][cb] + redR[3][p][cb];
      }
      const int pix = h*192 + w;
      #pragma unroll
      for (int b = 0; b < 2; ++b)
        #pragma unroll
        for (int c = 0; c < 2; ++c) {
          const int cb = b*2 + c;
          out[((size_t)b*NPIX + pix)*2 + c] = sqrtf(re[cb]*re[cb] + im[cb]*im[cb]);
        }
    }
    __syncthreads();
  }
}

// ======================= standalone kernels (R15 fallback) ==================

__global__ __launch_bounds__(256) void phase_kernel(
    const float* __restrict__ points, const float* __restrict__ x,
    unsigned short* __restrict__ BT, unsigned short* __restrict__ CxT,
    unsigned short* __restrict__ SxT, unsigned short* __restrict__ Am,
    unsigned short* __restrict__ XT, float* __restrict__ kyv) {
  const int v2 = blockIdx.x;
  const int role = blockIdx.y;
  const int t = threadIdx.x;
  if (role == 8) {
    for (int idx = v2*256 + t; idx < 768*192; idx += 65*256) {
      const int n = idx / 192, h = idx - n*192;
      const int cb = n / 192, w = n - cb*192;
      const int b = cb >> 1, c = cb & 1;
      XT[idx] = f2b(x[(((size_t)b*HH + h)*WW + w)*2 + c]);
    }
    for (int idx = v2*256 + t; idx < M2P; idx += 65*256) {
      if (idx < M2) {
        const int v2b = idx / HALFT, tb = idx - v2b*HALFT;
        kyv[idx] = points[(v2b*NSAMP + tb)*2 + 1];
      } else {
        kyv[idx] = 0.f;
      }
    }
    return;
  }
  if (t >= HALFT) return;
  if (role < 4) {
    const int hsplit = role;
    const float kx = points[(v2*NSAMP + t)*2 + 0];
    const int m2 = v2*HALFT + t;
    const int h0 = hsplit*48;
    float cr, ci; __sincosf(kx*(float)(h0-96), &ci, &cr);
    float dr, di; __sincosf(kx, &di, &dr);
    u16x8 pc, ps;
    for (int j = 0; j < 48; ++j) {
      const int h = h0 + j;
      CxT[(size_t)h*M2P + m2] = f2b(cr);
      SxT[(size_t)h*M2P + m2] = f2b(ci);
      pc[j&7] = f2b(cr); ps[j&7] = f2b(ci);
      if ((j&7) == 7) {
        *(u16x8*)(Am + (size_t)m2*192 + (h-7))         = pc;
        *(u16x8*)(Am + (size_t)(12672+m2)*192 + (h-7)) = ps;
      }
      rot(cr, ci, dr, di);
    }
  } else {
    const int wsplit = role - 4;
    const float ky = points[(v2*NSAMP + t)*2 + 1];
    const int kap = v2*HALFT + t;
    const int w0 = wsplit*48;
    float cr, ci; __sincosf(ky*(float)(w0-96), &ci, &cr);
    float dr, di; __sincosf(ky, &di, &dr);
    for (int j = 0; j < 48; ++j) {
      BT[(size_t)(w0+j)*KTOT + kap]       = f2b(cr);
      BT[(size_t)(w0+j)*KTOT + M2P + kap] = f2b(ci);
      rot(cr, ci, dr, di);
    }
  }
}

__global__ __launch_bounds__(256) void gemm1_kernel(
    const unsigned short* __restrict__ Am, const unsigned short* __restrict__ XT,
    const float* __restrict__ kyv, float* __restrict__ Abuf) {
  __shared__ float lds[2][128][2];
  const int L = blockIdx.x;
  const int idx0 = (L & 7)*99 + (L >> 3);
  const int mt = idx0 >> 2;
  const int cb = idx0 & 3;
  const int wv = threadIdx.x >> 6;
  const int lane = threadIdx.x & 63;
  const int r = lane & 15, kg = lane >> 4;
  const int mhalf = wv >> 1;
  const int whalf = wv & 1;
  const int mbase = mt*128 + mhalf*64;
  const int wbase = whalf*96;
  const int nbase = cb*192 + wbase;

  f32x4 acc[4][6];
  #pragma unroll
  for (int a = 0; a < 4; ++a)
    #pragma unroll
    for (int b = 0; b < 6; ++b) acc[a][b] = (f32x4){0.f,0.f,0.f,0.f};

  const unsigned short* Ap = Am + (size_t)(mbase + r)*192 + kg*8;
  const unsigned short* Bp = XT + (size_t)(nbase + r)*192 + kg*8;
  #pragma unroll
  for (int ks = 0; ks < 6; ++ks) {
    bf16x8 af[4], bfr[6];
    #pragma unroll
    for (int mf = 0; mf < 4; ++mf)
      af[mf] = *(const bf16x8*)(Ap + (size_t)mf*16*192 + ks*32);
    #pragma unroll
    for (int nf = 0; nf < 6; ++nf)
      bfr[nf] = *(const bf16x8*)(Bp + (size_t)nf*16*192 + ks*32);
    #pragma unroll
    for (int mf = 0; mf < 4; ++mf)
      #pragma unroll
      for (int nf = 0; nf < 6; ++nf)
        acc[mf][nf] = __builtin_amdgcn_mfma_f32_16x16x32_bf16(
            af[mf], bfr[nf], acc[mf][nf], 0, 0, 0);
  }

  const bool isCx = (mt < 99);
  const int m2w = mbase - (isCx ? 0 : 12672);
  float accA[16], accB[16];
  #pragma unroll
  for (int mf = 0; mf < 4; ++mf)
    #pragma unroll
    for (int reg = 0; reg < 4; ++reg) {
      const int m2 = m2w + mf*16 + kg*4 + reg;
      const float ky = kyv[m2];
      float a0 = 0.f, b0 = 0.f;
      #pragma unroll
      for (int nf = 0; nf < 6; ++nf) {
        const float wo = (float)(wbase + nf*16 + r - 96);
        float sy, cy; __sincosf(ky*wo, &sy, &cy);
        const float g = acc[mf][nf][reg];
        a0 = fmaf(g, cy, a0);
        b0 = fmaf(g, sy, b0);
      }
      accA[mf*4+reg] = a0; accB[mf*4+reg] = b0;
    }
  #pragma unroll
  for (int msk = 1; msk <= 8; msk <<= 1) {
    #pragma unroll
    for (int i = 0; i < 16; ++i) {
      accA[i] += __shfl_xor(accA[i], msk);
      accB[i] += __shfl_xor(accB[i], msk);
    }
  }
  if (r == 0) {
    #pragma unroll
    for (int mf = 0; mf < 4; ++mf)
      #pragma unroll
      for (int reg = 0; reg < 4; ++reg) {
        const int mloc = mhalf*64 + mf*16 + kg*4 + reg;
        lds[whalf][mloc][0] = accA[mf*4+reg];
        lds[whalf][mloc][1] = accB[mf*4+reg];
      }
  }
  __syncthreads();
  {
    const int tid = threadIdx.x;
    const int mloc = tid >> 1, slot = tid & 1;
    const float val = lds[0][mloc][slot] + lds[1][mloc][slot];
    const int m2 = mt*128 + mloc - (isCx ? 0 : 12672);
    const int oidx = isCx ? (slot ? 3 : 0) : (slot ? 1 : 2);
    Abuf[((size_t)cb*M2P + m2)*4 + oidx] = val;
  }
}

__global__ __launch_bounds__(256) void tmat_kernel(
    const float* __restrict__ Abuf, const float* __restrict__ weights,
    const unsigned short* __restrict__ CxT, const unsigned short* __restrict__ SxT,
    unsigned short* __restrict__ A, float* __restrict__ K2edge) {
  const int m2 = blockIdx.x*256 + threadIdx.x;
  if (m2 >= M2P) return;
  const int role = blockIdx.y;
  if (role == 192) {
    if (m2 >= M2) return;
    const int v2 = m2 / HALFT, t = m2 - v2*HALFT;
    if (t != 0 && t != 192) return;
    const float f = weights[t] * (1.0f/36864.0f);
    const bool hp = (v2 >= 1 && v2 <= 63);
    const int d = (t == 0) ? 0 : 1;
    #pragma unroll
    for (int cb = 0; cb < 4; ++cb) {
      const float4 Av = *(const float4*)(Abuf + ((size_t)cb*M2P + m2)*4);
      const float A1 = Av.x, A2 = Av.y, A3 = Av.z, A4 = Av.w;
      float* e = K2edge + ((v2*2 + d)*4 + cb)*2;
      e[0] = f*(A1 - A2); e[1] = -f*(A3 + A4);
      if (hp) {
        float* e2 = K2edge + (((128 - v2)*2 + d)*4 + cb)*2;
        e2[0] = f*(A1 + A2); e2[1] = f*(A3 - A4);
      }
    }
    return;
  }
  const int h = role;
  if (m2 >= M2) {
    #pragma unroll
    for (int cb = 0; cb < 4; ++cb) {
      unsigned short* Arow = A + (size_t)(cb*192 + h)*KTOT;
      Arow[m2] = 0; Arow[M2P + m2] = 0;
    }
    return;
  }
  const int v2 = m2 / HALFT, t = m2 - v2*HALFT;
  float f = weights[t] * (1.0f/36864.0f);
  if (t != 0 && t != 192) f *= 2.0f;
  const bool hp = (v2 >= 1 && v2 <= 63);
  const float cx = b2f(CxT[(size_t)h*M2P + m2]);
  const float sx = b2f(SxT[(size_t)h*M2P + m2]);
  #pragma unroll
  for (int cb = 0; cb < 4; ++cb) {
    const float4 Av = *(const float4*)(Abuf + ((size_t)cb*M2P + m2)*4);
    const float A1 = Av.x, A2 = Av.y, A3 = Av.z, A4 = Av.w;
    float p0, p1, q0, q1;
    if (hp) {
      p0 = 2.f*f*A1; p1 = 2.f*f*A3; q0 = 2.f*f*A4; q1 = 2.f*f*A2;
    } else {
      const float kr = f*(A1 - A2), ki = -f*(A3 + A4);
      p0 = kr; p1 = -ki; q0 = -ki; q1 = -kr;
    }
    unsigned short* Arow = A + (size_t)(cb*192 + h)*KTOT;
    Arow[m2]       = f2b(p0*cx + p1*sx);
    Arow[M2P + m2] = f2b(q0*cx + q1*sx);
  }
}

__global__ __launch_bounds__(256) void adj_gemm(
    const unsigned short* __restrict__ A, const unsigned short* __restrict__ BT,
    unsigned short* __restrict__ partials) {
  const int L = blockIdx.x;
  const int xcd = L & 7, slot = L >> 3;
  const int g = slot / 6;
  const int kc = g*8 + xcd;
  if (kc >= NSPLITK) return;
  const int mt = slot - g*6;
  const int wv = threadIdx.x >> 6;
  const int lane = threadIdx.x & 63;
  const int r = lane & 15, kg = lane >> 4;
  const int jbase = mt*128 + (wv>>1)*64;
  const int wbase = (wv&1)*96;
  const int kb = kc*768 + kg*8;

  f32x4 acc[4][6];
  #pragma unroll
  for (int a = 0; a < 4; ++a)
    #pragma unroll
    for (int b = 0; b < 6; ++b) acc[a][b] = (f32x4){0.f,0.f,0.f,0.f};

  const unsigned short* Ap = A + (size_t)(jbase + r)*KTOT + kb;
  const unsigned short* Bp = BT + (size_t)(wbase + r)*KTOT + kb;
  for (int ks = 0; ks < 24; ++ks) {
    bf16x8 af[4], bfr[6];
    #pragma unroll
    for (int mf = 0; mf < 4; ++mf)
      af[mf] = *(const bf16x8*)(Ap + (size_t)mf*16*KTOT + ks*32);
    #pragma unroll
    for (int nf = 0; nf < 6; ++nf)
      bfr[nf] = *(const bf16x8*)(Bp + (size_t)nf*16*KTOT + ks*32);
    #pragma unroll
    for (int mf = 0; mf < 4; ++mf)
      #pragma unroll
      for (int nf = 0; nf < 6; ++nf)
        acc[mf][nf] = __builtin_amdgcn_mfma_f32_16x16x32_bf16(
            af[mf], bfr[nf], acc[mf][nf], 0, 0, 0);
  }
  unsigned short* base = partials + (size_t)kc*147456;
  #pragma unroll
  for (int mf = 0; mf < 4; ++mf)
    #pragma unroll
    for (int nf = 0; nf < 6; ++nf) {
      const int w = wbase + nf*16 + r;
      const int j = jbase + mf*16 + kg*4;
      ushort4 u = make_ushort4(f2b(acc[mf][nf][0]), f2b(acc[mf][nf][1]),
                               f2b(acc[mf][nf][2]), f2b(acc[mf][nf][3]));
      *(ushort4*)(base + (size_t)w*768 + j) = u;
    }
}

__global__ __launch_bounds__(256) void finish_kernel(
    const unsigned short* __restrict__ BT, const unsigned short* __restrict__ CxT,
    const unsigned short* __restrict__ SxT, const float* __restrict__ K2edge,
    const unsigned short* __restrict__ partials, float* __restrict__ out) {
  __shared__ float cxs[65][8], sxs[65][8], cys[65][8], sys[65][8];
  __shared__ float redI[4][64][4], redR[4][64][4];
  const int bx = blockIdx.x;
  const int h0 = (bx/24)*8, w0 = (bx%24)*8;
  const int tid = threadIdx.x;
  for (int i = tid; i < 65*8; i += 256) {
    const int v2 = i >> 3, e = i & 7;
    const int kap = v2*HALFT;
    cxs[v2][e] = b2f(CxT[(size_t)(h0+e)*M2P + kap]);
    sxs[v2][e] = b2f(SxT[(size_t)(h0+e)*M2P + kap]);
    cys[v2][e] = b2f(BT[(size_t)(w0+e)*KTOT + kap]);
    sys[v2][e] = b2f(BT[(size_t)(w0+e)*KTOT + M2P + kap]);
  }
  __syncthreads();
  const int g = tid >> 6, hi = (tid >> 3) & 7, wi = tid & 7;
  const int h = h0 + hi, w = w0 + wi;
  float im[4] = {0,0,0,0};
  for (int v = g*32; v < g*32 + 32; ++v) {
    const int v2 = (v <= 64) ? v : 128 - v;
    const float sg = (v <= 64) ? 1.f : -1.f;
    const float cx = cxs[v2][hi], sx = sg*sxs[v2][hi];
    const float cy = cys[v2][wi], sy = sys[v2][wi];
    const float t1 = cx*sy + sx*cy;
    const float t2 = cx*cy - sx*sy;
    const int idx = v*16;
    #pragma unroll
    for (int cb = 0; cb < 4; ++cb)
      im[cb] += K2edge[idx + cb*2]*t1 + K2edge[idx + cb*2 + 1]*t2;
  }
  float re[4] = {0,0,0,0};
  for (int kc = g; kc < NSPLITK; kc += 4) {
    const unsigned short* p = partials + (size_t)kc*147456 + (size_t)w*768;
    #pragma unroll
    for (int cb = 0; cb < 4; ++cb)
      re[cb] += b2f(p[cb*192 + h]);
  }
  const int p = tid & 63;
  #pragma unroll
  for (int cb = 0; cb < 4; ++cb) { redI[g][p][cb] = im[cb]; redR[g][p][cb] = re[cb]; }
  __syncthreads();
  if (g == 0) {
    #pragma unroll
    for (int cb = 0; cb < 4; ++cb) {
      im[cb] += redI[1][p][cb] + redI[2][p][cb] + redI[3][p][cb];
      re[cb] += redR[1][p][cb] + redR[2][p][cb] + redR[3][p][cb];
    }
    const int pix = h*192 + w;
    #pragma unroll
    for (int b = 0; b < 2; ++b)
      #pragma unroll
      for (int c = 0; c < 2; ++c) {
        const int cb = b*2 + c;
        out[((size_t)b*NPIX + pix)*2 + c] = sqrtf(re[cb]*re[cb] + im[cb]*im[cb]);
      }
  }
}

// ---------------- r2 fallback (tiny ws) ----------------

template <int HPER>
__global__ __launch_bounds__(192) void fwd_kernel(
    const float* __restrict__ x, const float* __restrict__ points,
    float* __restrict__ kpart) {
  const int v = blockIdx.x;
  const int split = blockIdx.y;
  const int t = threadIdx.x;
  const int m = v*NSAMP + t;
  const float kx = points[2*m+0];
  const float ky = points[2*m+1];
  const int h0 = split*HPER;

  float kr[4] = {0,0,0,0}, ki[4] = {0,0,0,0};
  float cyr, cyi; __sincosf(96.0f*ky, &cyi, &cyr);
  float dyr, dyi; __sincosf(-ky, &dyi, &dyr);
  float cx0r, cx0i; __sincosf(kx*(float)(96-h0), &cx0i, &cx0r);
  float dxr, dxi; __sincosf(-kx, &dxi, &dxr);

  for (int wp = 0; wp < 96; ++wp) {
    const int w0 = wp*2;
    float g0r[4]={0,0,0,0}, g0i[4]={0,0,0,0};
    float g1r[4]={0,0,0,0}, g1i[4]={0,0,0,0};
    float cxr = cx0r, cxi = cx0i;
    const float* p0 = x + (h0*WW + w0)*2;
    const float* p1 = p0 + HH*WW*2;
    #pragma unroll 4
    for (int h = 0; h < HPER; ++h) {
      float4 a = *(const float4*)(p0 + h*(WW*2));
      float4 b = *(const float4*)(p1 + h*(WW*2));
      g0r[0] += a.x*cxr; g0i[0] += a.x*cxi;
      g0r[1] += a.y*cxr; g0i[1] += a.y*cxi;
      g1r[0] += a.z*cxr; g1i[0] += a.z*cxi;
      g1r[1] += a.w*cxr; g1i[1] += a.w*cxi;
      g0r[2] += b.x*cxr; g0i[2] += b.x*cxi;
      g0r[3] += b.y*cxr; g0i[3] += b.y*cxi;
      g1r[2] += b.z*cxr; g1i[2] += b.z*cxi;
      g1r[3] += b.w*cxr; g1i[3] += b.w*cxi;
      rot(cxr, cxi, dxr, dxi);
    }
    #pragma unroll
    for (int cb = 0; cb < 4; ++cb) {
      kr[cb] += g0r[cb]*cyr - g0i[cb]*cyi;
      ki[cb] += g0r[cb]*cyi + g0i[cb]*cyr;
    }
    rot(cyr, cyi, dyr, dyi);
    #pragma unroll
    for (int cb = 0; cb < 4; ++cb) {
      kr[cb] += g1r[cb]*cyr - g1i[cb]*cyi;
      ki[cb] += g1r[cb]*cyi + g1i[cb]*cyr;
    }
    rot(cyr, cyi, dyr, dyi);
  }
  float* o = kpart + (((split*NVIEWS + v)*192 + t)*4)*2;
  #pragma unroll
  for (int cb = 0; cb < 4; ++cb) { o[2*cb] = kr[cb]; o[2*cb+1] = ki[cb]; }
}

__global__ __launch_bounds__(256) void dc_kernel(
    const float* __restrict__ x, float* __restrict__ dcsum) {
  const int tid = threadIdx.x;
  float s0=0.f, s1=0.f, s2=0.f, s3=0.f;
  for (int i = tid; i < NPIX; i += 256) {
    float2 a = *(const float2*)(x + i*2);
    float2 b = *(const float2*)(x + HH*WW*2 + i*2);
    s0 += a.x; s1 += a.y; s2 += b.x; s3 += b.y;
  }
  #pragma unroll
  for (int off = 32; off > 0; off >>= 1) {
    s0 += __shfl_down(s0, off);
    s1 += __shfl_down(s1, off);
    s2 += __shfl_down(s2, off);
    s3 += __shfl_down(s3, off);
  }
  __shared__ float red[4][4];
  const int wv = tid >> 6, ln = tid & 63;
  if (ln == 0) { red[0][wv]=s0; red[1][wv]=s1; red[2][wv]=s2; red[3][wv]=s3; }
  __syncthreads();
  if (tid < 4) {
    float tot = red[tid][0]+red[tid][1]+red[tid][2]+red[tid][3];
    dcsum[2*tid] = tot; dcsum[2*tid+1] = 0.0f;
  }
}

__global__ __launch_bounds__(256) void combine_kernel(
    const float* __restrict__ kpart, const float* __restrict__ dcsum,
    const float* __restrict__ weights, float* __restrict__ K2, int nsplit) {
  const int idx = blockIdx.x*256 + threadIdx.x;
  if (idx >= NVIEWS*HALFT) return;
  const int v = idx / HALFT, t = idx % HALFT;
  float f = weights[t] * (1.0f/36864.0f);
  if (t != 0 && t != 192) f *= 2.0f;
  float o[8];
  if (t == 192) {
    #pragma unroll
    for (int cb = 0; cb < 4; ++cb) { o[2*cb] = f*dcsum[2*cb]; o[2*cb+1] = f*dcsum[2*cb+1]; }
  } else {
    #pragma unroll
    for (int cb = 0; cb < 4; ++cb) {
      float ar = 0.f, ai = 0.f;
      for (int s = 0; s < nsplit; ++s) {
        const float* p = kpart + (((s*NVIEWS + v)*192 + t)*4 + cb)*2;
        ar += p[0]; ai += p[1];
      }
      o[2*cb] = f*ar; o[2*cb+1] = f*ai;
    }
  }
  float* q = K2 + idx*8;
  #pragma unroll
  for (int j = 0; j < 8; ++j) q[j] = o[j];
}

template <int VPC>
__global__ __launch_bounds__(256) void adj_kernel(
    const float* __restrict__ K2, const float* __restrict__ points,
    float* __restrict__ imgpart) {
  const int pix = blockIdx.x*256 + threadIdx.x;
  const int chunk = blockIdx.y;
  const float nh = (float)(pix / WW - 96);
  const float nw = (float)(pix % WW - 96);
  float re[4] = {0,0,0,0}, im[4] = {0,0,0,0};
  const float INVPI = 0.3183098861837907f;
  const float PI192 = 3.14159265358979f / 192.0f;
  for (int v = chunk*VPC; v < chunk*VPC + VPC; ++v) {
    const float ct = -points[2*(v*NSAMP)+0] * INVPI;
    const float st = -points[2*(v*NSAMP)+1] * INVPI;
    const float alpha = ct*nh + st*nw;
    const float delta = alpha * PI192;
    float dr, di; __sincosf(delta, &di, &dr);
    float c0r, c0i; __sincosf(-192.0f*delta, &c0i, &c0r);
    const float* Kv = K2 + v*HALFT*8;
    #pragma unroll
    for (int cb = 0; cb < 4; ++cb) {
      float a = Kv[2*cb], b = Kv[2*cb+1];
      re[cb] += a*c0r - b*c0i;
      im[cb] += a*c0i + b*c0r;
    }
    float d2r = dr*dr - di*di, d2i = 2.0f*dr*di;
    float ar = c0r*dr - c0i*di, ai = c0r*di + c0i*dr;
    float br = ar*dr - ai*di,  bi = ar*di + ai*dr;
    for (int i = 0; i < 95; ++i) {
      const float* ka = Kv + (2*i+1)*8;
      const float* kb = Kv + (2*i+2)*8;
      #pragma unroll
      for (int cb = 0; cb < 4; ++cb)
        re[cb] += ka[2*cb]*ar - ka[2*cb+1]*ai;
      #pragma unroll
      for (int cb = 0; cb < 4; ++cb)
        re[cb] += kb[2*cb]*br - kb[2*cb+1]*bi;
      rot(ar, ai, d2r, d2i);
      rot(br, bi, d2r, d2i);
    }
    {
      const float* ka = Kv + 191*8;
      #pragma unroll
      for (int cb = 0; cb < 4; ++cb)
        re[cb] += ka[2*cb]*ar - ka[2*cb+1]*ai;
    }
    const float* kd = Kv + 192*8;
    #pragma unroll
    for (int cb = 0; cb < 4; ++cb) { re[cb] += kd[2*cb]; im[cb] += kd[2*cb+1]; }
  }
  float* o = imgpart + (chunk*NPIX + pix)*8;
  #pragma unroll
  for (int cb = 0; cb < 4; ++cb) { o[2*cb] = re[cb]; o[2*cb+1] = im[cb]; }
}

__global__ __launch_bounds__(256) void out_fb_kernel(
    const float* __restrict__ imgpart, float* __restrict__ out, int nchunk) {
  const int pix = blockIdx.x*256 + threadIdx.x;
  float re[4] = {0,0,0,0}, im[4] = {0,0,0,0};
  for (int ch = 0; ch < nchunk; ++ch) {
    const float* p = imgpart + (ch*NPIX + pix)*8;
    #pragma unroll
    for (int cb = 0; cb < 4; ++cb) { re[cb] += p[2*cb]; im[cb] += p[2*cb+1]; }
  }
  #pragma unroll
  for (int b = 0; b < 2; ++b)
    #pragma unroll
    for (int c = 0; c < 2; ++c) {
      const int cb = b*2 + c;
      out[(b*NPIX + pix)*2 + c] = sqrtf(re[cb]*re[cb] + im[cb]*im[cb]);
    }
}

extern "C" void kernel_launch(void* const* d_in, const int* in_sizes, int n_in,
                              void* d_out, int out_size, void* d_ws, size_t ws_size,
                              hipStream_t stream) {
  const float* x       = (const float*)d_in[0];
  const float* points  = (const float*)d_in[1];
  const float* weights = (const float*)d_in[2];
  float* out = (float*)d_out;

  // byte layout (same as R15)
  const size_t OFF_S   = 20334080ull;
  const size_t SZ_AADJ = 38928384ull;
  const size_t NEED    = OFF_S + SZ_AADJ + 9732096ull;

  if (ws_size >= NEED) {
    char* wsb = (char*)d_ws;
    unsigned short* BT   = (unsigned short*)(wsb + 0);
    unsigned short* CxT  = (unsigned short*)(wsb + 9732096);
    unsigned short* SxT  = (unsigned short*)(wsb + 14598144);
    float* K2edge        = (float*)(wsb + 19464192);
    float* kyv           = (float*)(wsb + 19472384);
    float* Abuf          = (float*)(wsb + 19523072);
    char* S              = wsb + OFF_S;
    unsigned short* Am   = (unsigned short*)(S + 0);
    unsigned short* XT   = (unsigned short*)(S + 9732096);
    unsigned short* Aadj = (unsigned short*)(S + 0);
    unsigned short* partials = (unsigned short*)(S + SZ_AADJ);

    // try the cooperative mega-kernel (capture-safe host queries only)
    hipError_t cerr = hipErrorUnknown;
    int dev = 0;
    if (hipGetDevice(&dev) == hipSuccess) {
      hipDeviceProp_t prop;
      if (hipGetDeviceProperties(&prop, dev) == hipSuccess &&
          prop.cooperativeLaunch) {
        int maxB = 0;
        if (hipOccupancyMaxActiveBlocksPerMultiprocessor(
                &maxB, mega_kernel, 256, 0) == hipSuccess && maxB > 0) {
          int G = maxB * prop.multiProcessorCount;
          if (G > 768) G = 768;
          if (G >= 64) {
            void* kargs[] = {
              (void*)&points, (void*)&x, (void*)&weights,
              (void*)&BT, (void*)&CxT, (void*)&SxT, (void*)&Am, (void*)&XT,
              (void*)&kyv, (void*)&Abuf, (void*)&Aadj, (void*)&K2edge,
              (void*)&partials, (void*)&out};
            cerr = hipLaunchCooperativeKernel(mega_kernel, dim3(G), dim3(256),
                                              kargs, 0, stream);
          }
        }
      }
    }
    if (cerr != hipSuccess) {
      // validated R15 5-kernel path
      phase_kernel<<<dim3(65,9), 256, 0, stream>>>(points, x, BT, CxT, SxT, Am, XT, kyv);
      gemm1_kernel<<<792, 256, 0, stream>>>(Am, XT, kyv, Abuf);
      tmat_kernel<<<dim3((M2P + 255)/256, 193), 256, 0, stream>>>(
          Abuf, weights, CxT, SxT, Aadj, K2edge);
      adj_gemm<<<240, 256, 0, stream>>>(Aadj, BT, partials);
      finish_kernel<<<576, 256, 0, stream>>>(BT, CxT, SxT, K2edge, partials, out);
    }
  } else {
    // r2 fallback path
    float* ws = (float*)d_ws;
    const size_t ws_floats = ws_size / sizeof(float);
    int nsplit = 16, nchunk = 16;
    auto need = [&](int ns, int nc) -> size_t {
      return (size_t)ns*196608 + 8 + 197632 + (size_t)nc*294912;
    };
    while (need(nsplit, nchunk) > ws_floats && nchunk > 1) nchunk >>= 1;
    while (need(nsplit, nchunk) > ws_floats && nsplit > 1) nsplit >>= 1;

    float* kpart   = ws;
    float* dcsum   = kpart + (size_t)nsplit*196608;
    float* K2      = dcsum + 8;
    float* imgpart = K2 + 197632;

    switch (nsplit) {
      case 16: fwd_kernel<12><<<dim3(NVIEWS,16), 192, 0, stream>>>(x, points, kpart); break;
      case 8:  fwd_kernel<24><<<dim3(NVIEWS,8),  192, 0, stream>>>(x, points, kpart); break;
      case 4:  fwd_kernel<48><<<dim3(NVIEWS,4),  192, 0, stream>>>(x, points, kpart); break;
      case 2:  fwd_kernel<96><<<dim3(NVIEWS,2),  192, 0, stream>>>(x, points, kpart); break;
      default: fwd_kernel<192><<<dim3(NVIEWS,1), 192, 0, stream>>>(x, points, kpart); break;
    }
    dc_kernel<<<1, 256, 0, stream>>>(x, dcsum);
    combine_kernel<<<(NVIEWS*HALFT + 255)/256, 256, 0, stream>>>(
        kpart, dcsum, weights, K2, nsplit);
    switch (nchunk) {
      case 16: adj_kernel<8>  <<<dim3(NPIX/256,16), 256, 0, stream>>>(K2, points, imgpart); break;
      case 8:  adj_kernel<16> <<<dim3(NPIX/256,8),  256, 0, stream>>>(K2, points, imgpart); break;
      case 4:  adj_kernel<32> <<<dim3(NPIX/256,4),  256, 0, stream>>>(K2, points, imgpart); break;
      case 2:  adj_kernel<64> <<<dim3(NPIX/256,2),  256, 0, stream>>>(K2, points, imgpart); break;
      default: adj_kernel<128><<<dim3(NPIX/256,1),  256, 0, stream>>>(K2, points, imgpart); break;
    }
    out_fb_kernel<<<NPIX/256, 256, 0, stream>>>(imgpart, out, nchunk);
  }
}